// Round 3
// baseline (22078.818 us; speedup 1.0000x reference)
//
#include <hip/hip_runtime.h>
#include <hip/hip_cooperative_groups.h>
#include <stdint.h>

namespace cg = cooperative_groups;

typedef short bf16x8 __attribute__((ext_vector_type(8)));
typedef short s16x4 __attribute__((ext_vector_type(4)));
typedef float f32x4 __attribute__((ext_vector_type(4)));
typedef unsigned int u32;
typedef unsigned short u16;
typedef unsigned long long u64;

// ---------------- workspace layout (bytes) ----------------
#define OFF_WXT  0ull                  // [2][3][1536][1024] bf16  (Wx transposed)
#define OFF_WHF  18874368ull           // [3][2][32][3][16][64][8] bf16 (Wh frags)
#define OFF_PRJT 37748736ull           // [3][1024][1024] bf16 (proj_W^T)
#define OFF_IPJT 44040192ull           // [1024][1024] bf16 (in_proj_W^T)
#define OFF_XB   46137344ull           // [32768][1024] bf16 (activations)
#define OFF_G    113246208ull          // [2][512*96][1024] bf16 (gate-x tiles)
#define OFF_OCAT 314572800ull          // [32768][1024] bf16 (hf|hb)
#define OFF_INP  381681664ull          // [32768][1024] f32 (highway inputs)
#define OFF_HB   515899392ull          // [2][2][64][512] bf16 (h double-buf)
#define WS_NEED  516161536ull

__device__ __forceinline__ float b2f(u32 u){ return __uint_as_float(u<<16); }
__device__ __forceinline__ u16 f2b(float f){
  u32 i = __float_as_uint(f);
  return (u16)((i + 0x7FFFu + ((i>>16)&1u))>>16);
}
__device__ __forceinline__ float sigm(float x){ return 1.f/(1.f+__expf(-x)); }
__device__ __forceinline__ float tanh_f(float x){
  x = fminf(fmaxf(x,-15.f),15.f);
  float e = __expf(2.f*x);
  return (e-1.f)/(e+1.f);
}
__device__ __forceinline__ void gl_lds16(const void* g, void* l){
  __builtin_amdgcn_global_load_lds((const __attribute__((address_space(1))) u32*)g,
                                   (__attribute__((address_space(3))) u32*)l, 16, 0, 0);
}

// ---------------- prep kernels ----------------
__global__ void k_convx(const float* __restrict__ x, u16* __restrict__ xb){
  long i = (long)blockIdx.x*blockDim.x + threadIdx.x;   // exactly 33554432 threads
  xb[i] = f2b(x[i]);
}

__global__ void k_wxt(const float* __restrict__ fw, const float* __restrict__ bw, u16* __restrict__ out){
  long o = (long)blockIdx.x*blockDim.x + threadIdx.x;   // 9437184
  int k = (int)(o & 1023);
  long q = o >> 10;
  int nn = (int)(q % 1536); q /= 1536;
  int l = (int)(q % 3); int d = (int)(q / 3);
  const float* W = (d ? bw : fw) + (size_t)l*1536*1536;
  out[o] = f2b(W[(size_t)k*1536 + nn]);
}

__global__ void k_whf(const float* __restrict__ fw, const float* __restrict__ bw, u16* __restrict__ out){
  long o = (long)blockIdx.x*blockDim.x + threadIdx.x;   // exactly 4718592 threads
  int e = (int)(o & 7);
  int lane = (int)((o>>3) & 63);
  int kk = (int)((o>>9) & 15);
  long q = o >> 13;
  int g = (int)(q % 3); q /= 3;
  int wg = (int)(q % 32); q /= 32;
  int d = (int)(q % 2); int l = (int)(q / 2);
  const float* W = (d ? bw : fw) + (size_t)l*1536*1536;
  int row = 1024 + kk*32 + (lane>>4)*8 + e;
  int col = g*512 + wg*16 + (lane&15);
  out[o] = f2b(W[(size_t)row*1536 + col]);
}

__global__ void k_pjt(const float* __restrict__ pw, const float* __restrict__ ipw,
                      u16* __restrict__ pjt, u16* __restrict__ ipjt){
  long o = (long)blockIdx.x*blockDim.x + threadIdx.x;   // 4194304
  if (o < 3145728){
    int k = (int)(o & 1023); int nn = (int)((o>>10) & 1023); int l = (int)(o >> 20);
    pjt[o] = f2b(pw[((size_t)l<<20) + (size_t)k*1024 + nn]);
  } else {
    long o2 = o - 3145728;
    int k = (int)(o2 & 1023); int nn = (int)(o2 >> 10);
    ipjt[o2] = f2b(ipw[(size_t)k*1024 + nn]);
  }
}

// ---------------- tiled bf16 MFMA GEMM (B^T input), fused epilogues ----------------
template<int V>
__global__ __launch_bounds__(256)
void gemm_bt(const u16* __restrict__ A, const u16* __restrict__ Bt,
             const float* __restrict__ bias, int K,
             u16* __restrict__ Gout, int dir,
             float* __restrict__ inputs,
             const u16* __restrict__ ocat, u16* __restrict__ xbout,
             float* __restrict__ dout)
{
  __shared__ u16 As[128*64];
  __shared__ u16 Bs[128*64];
  const int tid = threadIdx.x, wid = tid>>6, lane = tid&63;
  const int wr = wid>>1, wc = wid&1;
  const int mblk = blockIdx.x & 255;
  const int nblk = blockIdx.x >> 8;
  f32x4 acc[4][4];
  #pragma unroll
  for (int i=0;i<4;i++)
    #pragma unroll
    for (int j=0;j<4;j++) acc[i][j] = (f32x4){0.f,0.f,0.f,0.f};
  const size_t Kb = (size_t)K*2;
  const char* Ab = (const char*)A + (size_t)(mblk*128)*Kb;
  const char* Bb = (const char*)Bt + (size_t)(nblk*128)*Kb;
  const int r8 = lane>>3, c8 = lane&7;
  for (int kt=0; kt<K/64; ++kt){
    __syncthreads();
    #pragma unroll
    for (int i=0;i<4;i++){
      const int instr = wid*4 + i;
      const int row = instr*8 + r8;
      const int so = (c8*16) ^ ((row&7)<<4);          // T2 swizzle via pre-swizzled src
      gl_lds16(Ab + (size_t)row*Kb + kt*128 + so, (char*)As + instr*1024);
      gl_lds16(Bb + (size_t)row*Kb + kt*128 + so, (char*)Bs + instr*1024);
    }
    __syncthreads();
    #pragma unroll
    for (int ks=0; ks<2; ++ks){
      bf16x8 af[4], bfv[4];
      #pragma unroll
      for (int mt=0;mt<4;mt++){
        int r = wr*64 + mt*16 + (lane&15);
        int kb = (ks*64 + ((lane>>4)*16)) ^ ((r&7)<<4);
        af[mt] = *(const bf16x8*)((const char*)As + r*128 + kb);
      }
      #pragma unroll
      for (int nt=0;nt<4;nt++){
        int r = wc*64 + nt*16 + (lane&15);
        int kb = (ks*64 + ((lane>>4)*16)) ^ ((r&7)<<4);
        bfv[nt] = *(const bf16x8*)((const char*)Bs + r*128 + kb);
      }
      #pragma unroll
      for (int mt=0;mt<4;mt++)
        #pragma unroll
        for (int nt=0;nt<4;nt++)
          acc[mt][nt] = __builtin_amdgcn_mfma_f32_16x16x32_bf16(af[mt], bfv[nt], acc[mt][nt], 0,0,0);
    }
  }
  const int mb = mblk*128 + wr*64;
  const int nb = nblk*128 + wc*64;
  #pragma unroll
  for (int nt=0;nt<4;nt++){
    const int n = nb + nt*16 + (lane&15);
    const float bv = bias[n];
    #pragma unroll
    for (int mt=0;mt<4;mt++){
      #pragma unroll
      for (int r=0;r<4;r++){
        const int m = mb + mt*16 + (lane>>4)*4 + r;
        float v = acc[mt][nt][r] + bv;
        if (V==0){
          int b = m >> 9, t = m & 511;
          int tp = dir ? (511 - t) : t;
          // tile = (tp, n>>4); within-tile layout keyed to lstm_rec's C-frag:
          // widx = [mt=b>>4][lane=((b>>2)&3)*16 + (n&15)][r=b&3]
          size_t tile = (size_t)tp*96 + (n>>4);
          int widx = ((b>>4)<<8) + (((b>>2)&3)<<6) + ((n&15)<<2) + (b&3);
          Gout[tile*1024 + widx] = f2b(v);
        } else if (V==1){
          inputs[(size_t)m*1024 + n] = v;
        } else {
          float g = sigm(v);
          size_t a = (size_t)m*1024 + n;
          float o = b2f((u32)ocat[a]);
          float nv = g*o + (1.f-g)*inputs[a];
          if (dout) dout[a] = nv;
          else { inputs[a] = nv; xbout[a] = f2b(nv); }
        }
      }
    }
  }
}

// ---------------- persistent recurrent kernel (cooperative) ----------------
// grid = 64 blocks x 256 threads. block = (dir d, column-group wg of 16 h-cols).
// waves 0-2 own gates i/j/o; each holds its Wh slice [512 x 16] in 16 B-frags.
// wave 3 helps stage h and run the cell update. Barrier = grid.sync().
__global__ __launch_bounds__(256, 1)
void lstm_rec(const u16* __restrict__ Whf, const u16* __restrict__ G,
              u16* __restrict__ hb,
              const float* __restrict__ h0f_, const float* __restrict__ c0f_,
              const float* __restrict__ h0b_, const float* __restrict__ c0b_,
              u16* __restrict__ ocat)
{
  cg::grid_group grid = cg::this_grid();
  const int d = blockIdx.x >> 5, wg = blockIdx.x & 31;
  const int tid = threadIdx.x;
  const int wave = tid >> 6, lane = tid & 63;
  const int n0 = wg * 16;
  __shared__ u16 hlds[64*520];          // padded row stride 1040B (16B-aligned, bank-shift 4)
  __shared__ float ldsg[3][64][17];
  __shared__ float ldsc[64][17];

  bf16x8 w[16];
  if (wave < 3){
    const u16* wb = Whf + (((size_t)(d*32+wg)*3 + wave)*1024 + lane)*8;
    #pragma unroll
    for (int kk=0;kk<16;kk++) w[kk] = *(const bf16x8*)(wb + kk*512);
  }
  const float* h0 = d ? h0b_ : h0f_;
  const float* c0 = d ? c0b_ : c0f_;
  u16* hbd = hb + (size_t)d*65536;      // [2 buf][64][512] bf16

  for (int p=tid; p<512; p+=256){
    int b = p>>3, c2 = (p&7)*2;
    u32 pk = (u32)f2b(h0[n0+c2]) | ((u32)f2b(h0[n0+c2+1])<<16);
    *(u32*)(hbd + (size_t)b*512 + n0 + c2) = pk;   // buffer 0
    ldsc[b][c2]   = c0[n0+c2];
    ldsc[b][c2+1] = c0[n0+c2+1];
  }
  grid.sync();

  const int ntg = wave*32 + wg;
  const int c16 = (lane>>4)*16;
  for (int t=0; t<512; ++t){
    // ---- stage h[64][512] (this dir) into LDS ----
    const u64* hsrc = (const u64*)(hbd + (size_t)(t&1)*32768);
    #pragma unroll
    for (int it=0; it<32; ++it){
      int idx = tid + it*256;           // 8192 u64 total
      int row = idx >> 7;
      int cb  = (idx & 127) << 3;
      *(u64*)((char*)hlds + row*1040 + cb) = hsrc[idx];
    }
    // ---- per-wave gate-x fragment (coalesced 8B/lane) ----
    s16x4 gv[4];
    if (wave < 3){
      const u16* Gt = G + ((size_t)(d*512 + t)*96 + ntg)*1024;
      #pragma unroll
      for (int mt=0;mt<4;mt++)
        gv[mt] = *(const s16x4*)(Gt + mt*256 + (lane<<2));
    }
    __syncthreads();

    if (wave < 3){
      f32x4 acc0={0.f,0.f,0.f,0.f}, acc1={0.f,0.f,0.f,0.f}, acc2={0.f,0.f,0.f,0.f}, acc3={0.f,0.f,0.f,0.f};
      #pragma unroll
      for (int kk=0;kk<16;kk++){
        const char* base = (const char*)hlds + kk*64 + c16;
        bf16x8 a0 = *(const bf16x8*)(base + ((lane&15)     )*1040);
        bf16x8 a1 = *(const bf16x8*)(base + ((lane&15) + 16)*1040);
        bf16x8 a2 = *(const bf16x8*)(base + ((lane&15) + 32)*1040);
        bf16x8 a3 = *(const bf16x8*)(base + ((lane&15) + 48)*1040);
        acc0 = __builtin_amdgcn_mfma_f32_16x16x32_bf16(a0, w[kk], acc0, 0,0,0);
        acc1 = __builtin_amdgcn_mfma_f32_16x16x32_bf16(a1, w[kk], acc1, 0,0,0);
        acc2 = __builtin_amdgcn_mfma_f32_16x16x32_bf16(a2, w[kk], acc2, 0,0,0);
        acc3 = __builtin_amdgcn_mfma_f32_16x16x32_bf16(a3, w[kk], acc3, 0,0,0);
      }
      const int bb = (lane>>4)*4;
      #pragma unroll
      for (int r=0;r<4;r++){
        ldsg[wave][bb+r     ][lane&15] = acc0[r] + b2f((u32)(u16)gv[0][r]);
        ldsg[wave][bb+r + 16][lane&15] = acc1[r] + b2f((u32)(u16)gv[1][r]);
        ldsg[wave][bb+r + 32][lane&15] = acc2[r] + b2f((u32)(u16)gv[2][r]);
        ldsg[wave][bb+r + 48][lane&15] = acc3[r] + b2f((u32)(u16)gv[3][r]);
      }
    }
    __syncthreads();

    // ---- cell update + write h(t+1), ocat ----
    const int t_o = d ? (511 - t) : t;
    u16* hnxt = hbd + (size_t)((t+1)&1)*32768;
    for (int p=tid; p<512; p+=256){
      int b = p>>3, c2 = (p&7)*2;
      float i0 = sigm(ldsg[0][b][c2]);
      float i1 = sigm(ldsg[0][b][c2+1]);
      float cn0 = (1.f-i0)*ldsc[b][c2]   + i0*tanh_f(ldsg[1][b][c2]);
      float cn1 = (1.f-i1)*ldsc[b][c2+1] + i1*tanh_f(ldsg[1][b][c2+1]);
      ldsc[b][c2] = cn0; ldsc[b][c2+1] = cn1;
      float hv0 = tanh_f(cn0)*sigm(ldsg[2][b][c2]);
      float hv1 = tanh_f(cn1)*sigm(ldsg[2][b][c2+1]);
      u32 pk = (u32)f2b(hv0) | ((u32)f2b(hv1)<<16);
      *(u32*)(hnxt + (size_t)b*512 + n0 + c2) = pk;
      *(u32*)(ocat + (((size_t)(b*512 + t_o))<<10) + (d<<9) + n0 + c2) = pk;
    }
    grid.sync();
  }
}

extern "C" void kernel_launch(void* const* d_in, const int* in_sizes, int n_in,
                              void* d_out, int out_size, void* d_ws, size_t ws_size,
                              hipStream_t stream)
{
  (void)in_sizes; (void)n_in; (void)out_size;
  if (ws_size < WS_NEED) return;
  const float* x      = (const float*)d_in[0];
  const float* fw_W   = (const float*)d_in[1];
  const float* fw_b   = (const float*)d_in[2];
  const float* bw_W   = (const float*)d_in[3];
  const float* bw_b   = (const float*)d_in[4];
  const float* h0f    = (const float*)d_in[5];
  const float* c0f    = (const float*)d_in[6];
  const float* h0b    = (const float*)d_in[7];
  const float* c0b    = (const float*)d_in[8];
  const float* proj_W = (const float*)d_in[9];
  const float* proj_b = (const float*)d_in[10];
  const float* ipW    = (const float*)d_in[11];
  const float* ipb    = (const float*)d_in[12];
  char* ws = (char*)d_ws;
  u16* WXT  = (u16*)(ws + OFF_WXT);
  u16* WHF  = (u16*)(ws + OFF_WHF);
  u16* PRJT = (u16*)(ws + OFF_PRJT);
  u16* IPJT = (u16*)(ws + OFF_IPJT);
  u16* XB   = (u16*)(ws + OFF_XB);
  u16* GB   = (u16*)(ws + OFF_G);
  u16* OCAT = (u16*)(ws + OFF_OCAT);
  float* INP= (float*)(ws + OFF_INP);
  u16* HB   = (u16*)(ws + OFF_HB);

  k_convx<<<131072, 256, 0, stream>>>(x, XB);
  k_wxt<<<36864, 256, 0, stream>>>(fw_W, bw_W, WXT);
  k_whf<<<18432, 256, 0, stream>>>(fw_W, bw_W, WHF);
  k_pjt<<<16384, 256, 0, stream>>>(proj_W, ipW, PRJT, IPJT);

  gemm_bt<1><<<2048, 256, 0, stream>>>(XB, IPJT, ipb, 1024, nullptr, 0, INP, nullptr, nullptr, nullptr);

  for (int l=0; l<3; ++l){
    gemm_bt<0><<<3072, 256, 0, stream>>>(XB, WXT + (size_t)l*1572864, fw_b + l*1536, 1024,
                                         GB, 0, nullptr, nullptr, nullptr, nullptr);
    gemm_bt<0><<<3072, 256, 0, stream>>>(XB, WXT + (size_t)(3+l)*1572864, bw_b + l*1536, 1024,
                                         GB + 50331648ull, 1, nullptr, nullptr, nullptr, nullptr);
    {
      const u16* whfl = WHF + (size_t)l*1572864;
      const u16* gbp  = GB;
      u16* hbp = HB;
      const float* p1 = h0f + l*512;
      const float* p2 = c0f + l*512;
      const float* p3 = h0b + l*512;
      const float* p4 = c0b + l*512;
      u16* ocp = OCAT;
      void* args[] = { (void*)&whfl, (void*)&gbp, (void*)&hbp,
                       (void*)&p1, (void*)&p2, (void*)&p3, (void*)&p4, (void*)&ocp };
      hipLaunchCooperativeKernel((void*)lstm_rec, dim3(64), dim3(256), args, 0, stream);
    }
    gemm_bt<2><<<2048, 256, 0, stream>>>(OCAT, PRJT + (size_t)l*1048576, proj_b + l*1024, 1024,
                                         nullptr, 0, INP, OCAT, XB,
                                         (l==2) ? (float*)d_out : nullptr);
  }
}

// Round 4
// 18459.438 us; speedup vs baseline: 1.1961x; 1.1961x over previous
//
#include <hip/hip_runtime.h>
#include <stdint.h>

typedef short bf16x8 __attribute__((ext_vector_type(8)));
typedef short s16x4 __attribute__((ext_vector_type(4)));
typedef float f32x4 __attribute__((ext_vector_type(4)));
typedef unsigned int u32;
typedef unsigned short u16;
typedef unsigned long long u64;

// ---------------- workspace layout (bytes) ----------------
#define OFF_WXT  0ull                  // [2][3][1536][1024] bf16  (Wx transposed)
#define OFF_WHF  18874368ull           // [3][2][32][3][16][64][8] bf16 (Wh frags)
#define OFF_PRJT 37748736ull           // [3][1024][1024] bf16 (proj_W^T)
#define OFF_IPJT 44040192ull           // [1024][1024] bf16 (in_proj_W^T)
#define OFF_XB   46137344ull           // [32768][1024] bf16 (activations)
#define OFF_G    113246208ull          // [2][512*96][1024] bf16 (gate-x tiles)
#define OFF_OCAT 314572800ull          // [32768][1024] bf16 (hf|hb)
#define OFF_INP  381681664ull          // [32768][1024] f32 (highway inputs)
#define OFF_HB   515899392ull          // [2][2][64][512] bf16 (h double-buf)
#define OFF_CTR  516161536ull          // [3][2] barrier counters, 128B apart
#define WS_NEED  516165632ull

__device__ __forceinline__ float b2f(u32 u){ return __uint_as_float(u<<16); }
__device__ __forceinline__ u16 f2b(float f){
  u32 i = __float_as_uint(f);
  return (u16)((i + 0x7FFFu + ((i>>16)&1u))>>16);
}
__device__ __forceinline__ float sigm(float x){ return 1.f/(1.f+__expf(-x)); }
__device__ __forceinline__ float tanh_f(float x){
  x = fminf(fmaxf(x,-15.f),15.f);
  float e = __expf(2.f*x);
  return (e-1.f)/(e+1.f);
}
__device__ __forceinline__ void gl_lds16(const void* g, void* l){
  __builtin_amdgcn_global_load_lds((const __attribute__((address_space(1))) u32*)g,
                                   (__attribute__((address_space(3))) u32*)l, 16, 0, 0);
}

// ---------------- prep kernels ----------------
__global__ void k_convx(const float* __restrict__ x, u16* __restrict__ xb){
  long i = (long)blockIdx.x*blockDim.x + threadIdx.x;   // exactly 33554432 threads
  xb[i] = f2b(x[i]);
}

__global__ void k_wxt(const float* __restrict__ fw, const float* __restrict__ bw, u16* __restrict__ out){
  long o = (long)blockIdx.x*blockDim.x + threadIdx.x;   // 9437184
  int k = (int)(o & 1023);
  long q = o >> 10;
  int nn = (int)(q % 1536); q /= 1536;
  int l = (int)(q % 3); int d = (int)(q / 3);
  const float* W = (d ? bw : fw) + (size_t)l*1536*1536;
  out[o] = f2b(W[(size_t)k*1536 + nn]);
}

__global__ void k_whf(const float* __restrict__ fw, const float* __restrict__ bw, u16* __restrict__ out){
  long o = (long)blockIdx.x*blockDim.x + threadIdx.x;   // exactly 4718592 threads
  int e = (int)(o & 7);
  int lane = (int)((o>>3) & 63);
  int kk = (int)((o>>9) & 15);
  long q = o >> 13;
  int g = (int)(q % 3); q /= 3;
  int wg = (int)(q % 32); q /= 32;
  int d = (int)(q % 2); int l = (int)(q / 2);
  const float* W = (d ? bw : fw) + (size_t)l*1536*1536;
  int row = 1024 + kk*32 + (lane>>4)*8 + e;
  int col = g*512 + wg*16 + (lane&15);
  out[o] = f2b(W[(size_t)row*1536 + col]);
}

__global__ void k_pjt(const float* __restrict__ pw, const float* __restrict__ ipw,
                      u16* __restrict__ pjt, u16* __restrict__ ipjt){
  long o = (long)blockIdx.x*blockDim.x + threadIdx.x;   // 4194304
  if (o < 3145728){
    int k = (int)(o & 1023); int nn = (int)((o>>10) & 1023); int l = (int)(o >> 20);
    pjt[o] = f2b(pw[((size_t)l<<20) + (size_t)k*1024 + nn]);
  } else {
    long o2 = o - 3145728;
    int k = (int)(o2 & 1023); int nn = (int)(o2 >> 10);
    ipjt[o2] = f2b(ipw[(size_t)k*1024 + nn]);
  }
}

// ---------------- tiled bf16 MFMA GEMM (B^T input), fused epilogues ----------------
template<int V>
__global__ __launch_bounds__(256)
void gemm_bt(const u16* __restrict__ A, const u16* __restrict__ Bt,
             const float* __restrict__ bias, int K,
             u16* __restrict__ Gout, int dir,
             float* __restrict__ inputs,
             const u16* __restrict__ ocat, u16* __restrict__ xbout,
             float* __restrict__ dout)
{
  __shared__ u16 As[128*64];
  __shared__ u16 Bs[128*64];
  const int tid = threadIdx.x, wid = tid>>6, lane = tid&63;
  const int wr = wid>>1, wc = wid&1;
  const int mblk = blockIdx.x & 255;
  const int nblk = blockIdx.x >> 8;
  f32x4 acc[4][4];
  #pragma unroll
  for (int i=0;i<4;i++)
    #pragma unroll
    for (int j=0;j<4;j++) acc[i][j] = (f32x4){0.f,0.f,0.f,0.f};
  const size_t Kb = (size_t)K*2;
  const char* Ab = (const char*)A + (size_t)(mblk*128)*Kb;
  const char* Bb = (const char*)Bt + (size_t)(nblk*128)*Kb;
  const int r8 = lane>>3, c8 = lane&7;
  for (int kt=0; kt<K/64; ++kt){
    __syncthreads();
    #pragma unroll
    for (int i=0;i<4;i++){
      const int instr = wid*4 + i;
      const int row = instr*8 + r8;
      const int so = (c8*16) ^ ((row&7)<<4);          // T2 swizzle via pre-swizzled src
      gl_lds16(Ab + (size_t)row*Kb + kt*128 + so, (char*)As + instr*1024);
      gl_lds16(Bb + (size_t)row*Kb + kt*128 + so, (char*)Bs + instr*1024);
    }
    __syncthreads();
    #pragma unroll
    for (int ks=0; ks<2; ++ks){
      bf16x8 af[4], bfv[4];
      #pragma unroll
      for (int mt=0;mt<4;mt++){
        int r = wr*64 + mt*16 + (lane&15);
        int kb = (ks*64 + ((lane>>4)*16)) ^ ((r&7)<<4);
        af[mt] = *(const bf16x8*)((const char*)As + r*128 + kb);
      }
      #pragma unroll
      for (int nt=0;nt<4;nt++){
        int r = wc*64 + nt*16 + (lane&15);
        int kb = (ks*64 + ((lane>>4)*16)) ^ ((r&7)<<4);
        bfv[nt] = *(const bf16x8*)((const char*)Bs + r*128 + kb);
      }
      #pragma unroll
      for (int mt=0;mt<4;mt++)
        #pragma unroll
        for (int nt=0;nt<4;nt++)
          acc[mt][nt] = __builtin_amdgcn_mfma_f32_16x16x32_bf16(af[mt], bfv[nt], acc[mt][nt], 0,0,0);
    }
  }
  const int mb = mblk*128 + wr*64;
  const int nb = nblk*128 + wc*64;
  #pragma unroll
  for (int nt=0;nt<4;nt++){
    const int n = nb + nt*16 + (lane&15);
    const float bv = bias[n];
    #pragma unroll
    for (int mt=0;mt<4;mt++){
      #pragma unroll
      for (int r=0;r<4;r++){
        const int m = mb + mt*16 + (lane>>4)*4 + r;
        float v = acc[mt][nt][r] + bv;
        if (V==0){
          int b = m >> 9, t = m & 511;
          int tp = dir ? (511 - t) : t;
          size_t tile = (size_t)tp*96 + (n>>4);
          int widx = ((b>>4)<<8) + (((b>>2)&3)<<6) + ((n&15)<<2) + (b&3);
          Gout[tile*1024 + widx] = f2b(v);
        } else if (V==1){
          inputs[(size_t)m*1024 + n] = v;
        } else {
          float g = sigm(v);
          size_t a = (size_t)m*1024 + n;
          float o = b2f((u32)ocat[a]);
          float nv = g*o + (1.f-g)*inputs[a];
          if (dout) dout[a] = nv;
          else { inputs[a] = nv; xbout[a] = f2b(nv); }
        }
      }
    }
  }
}

// ---------------- persistent recurrent kernel ----------------
// grid = 64 blocks x 256 threads. block = (dir d, column-group wg of 16 h-cols).
// waves 0-2 own gates i/j/o; W_h slice [512x16] register-resident as 16 B-frags.
// Cross-block sync: per-direction monotone counter (agent atomics); h exchange
// via agent-scope (sc0 sc1) loads/stores -> coherence point LLC, no fences.
__global__ __launch_bounds__(256, 1)
void lstm_rec(const u16* __restrict__ Whf, const u16* __restrict__ G,
              u16* __restrict__ hb,
              const float* __restrict__ h0f_, const float* __restrict__ c0f_,
              const float* __restrict__ h0b_, const float* __restrict__ c0b_,
              u16* __restrict__ ocat, u32* __restrict__ ctr)
{
  const int d = blockIdx.x >> 5, wg = blockIdx.x & 31;
  const int tid = threadIdx.x;
  const int wave = tid >> 6, lane = tid & 63;
  const int n0 = wg * 16;
  __shared__ u16 hlds[64*520];          // padded row stride 1040B (16B-aligned)
  __shared__ float ldsg[3][64][17];
  __shared__ float ldsc[64][17];

  bf16x8 w[16];
  if (wave < 3){
    const u16* wb = Whf + (((size_t)(d*32+wg)*3 + wave)*1024 + lane)*8;
    #pragma unroll
    for (int kk=0;kk<16;kk++) w[kk] = *(const bf16x8*)(wb + kk*512);
  }
  const float* h0 = d ? h0b_ : h0f_;
  const float* c0 = d ? c0b_ : c0f_;
  u16* hbd = hb + (size_t)d*65536;      // [2 buf][64][512] bf16
  u32* ctrd = ctr + d*32;               // per-direction counter, 128B apart

  for (int p=tid; p<512; p+=256){
    int b = p>>3, c2 = (p&7)*2;
    u32 pk = (u32)f2b(h0[n0+c2]) | ((u32)f2b(h0[n0+c2+1])<<16);
    __hip_atomic_store((u32*)(hbd + (size_t)b*512 + n0 + c2), pk,
                       __ATOMIC_RELAXED, __HIP_MEMORY_SCOPE_AGENT);
    ldsc[b][c2]   = c0[n0+c2];
    ldsc[b][c2+1] = c0[n0+c2+1];
  }
  __syncthreads();                       // drains vmcnt per wave before barrier
  if (tid==0){
    __hip_atomic_fetch_add(ctrd, 1u, __ATOMIC_RELAXED, __HIP_MEMORY_SCOPE_AGENT);
    while (__hip_atomic_load(ctrd, __ATOMIC_RELAXED, __HIP_MEMORY_SCOPE_AGENT) < 32u) {}
  }
  asm volatile("" ::: "memory");
  __syncthreads();

  const int ntg = wave*32 + wg;
  // prefetch gate-x fragment for t=0
  s16x4 gv[4];
  if (wave < 3){
    const u16* Gt = G + ((size_t)(d*512 + 0)*96 + ntg)*1024;
    #pragma unroll
    for (int mt=0;mt<4;mt++) gv[mt] = *(const s16x4*)(Gt + mt*256 + (lane<<2));
  }

  const int c16 = (lane>>4)*16;
  for (int t=0; t<512; ++t){
    // ---- stage h[64][512] into LDS (agent-scope loads: fresh from LLC) ----
    const u64* hsrc = (const u64*)(hbd + (size_t)(t&1)*32768);
    #pragma unroll
    for (int it=0; it<32; ++it){
      int idx = tid + it*256;           // 8192 u64 total
      u64 v = __hip_atomic_load(hsrc + idx, __ATOMIC_RELAXED, __HIP_MEMORY_SCOPE_AGENT);
      int row = idx >> 7;
      int cb  = (idx & 127) << 3;
      *(u64*)((char*)hlds + row*1040 + cb) = v;
    }
    __syncthreads();

    if (wave < 3){
      f32x4 acc0={0.f,0.f,0.f,0.f}, acc1={0.f,0.f,0.f,0.f}, acc2={0.f,0.f,0.f,0.f}, acc3={0.f,0.f,0.f,0.f};
      #pragma unroll
      for (int kk=0;kk<16;kk++){
        const char* base = (const char*)hlds + kk*64 + c16;
        bf16x8 a0 = *(const bf16x8*)(base + ((lane&15)     )*1040);
        bf16x8 a1 = *(const bf16x8*)(base + ((lane&15) + 16)*1040);
        bf16x8 a2 = *(const bf16x8*)(base + ((lane&15) + 32)*1040);
        bf16x8 a3 = *(const bf16x8*)(base + ((lane&15) + 48)*1040);
        acc0 = __builtin_amdgcn_mfma_f32_16x16x32_bf16(a0, w[kk], acc0, 0,0,0);
        acc1 = __builtin_amdgcn_mfma_f32_16x16x32_bf16(a1, w[kk], acc1, 0,0,0);
        acc2 = __builtin_amdgcn_mfma_f32_16x16x32_bf16(a2, w[kk], acc2, 0,0,0);
        acc3 = __builtin_amdgcn_mfma_f32_16x16x32_bf16(a3, w[kk], acc3, 0,0,0);
      }
      const int bb = (lane>>4)*4;
      #pragma unroll
      for (int r=0;r<4;r++){
        ldsg[wave][bb+r     ][lane&15] = acc0[r] + b2f((u32)(u16)gv[0][r]);
        ldsg[wave][bb+r + 16][lane&15] = acc1[r] + b2f((u32)(u16)gv[1][r]);
        ldsg[wave][bb+r + 32][lane&15] = acc2[r] + b2f((u32)(u16)gv[2][r]);
        ldsg[wave][bb+r + 48][lane&15] = acc3[r] + b2f((u32)(u16)gv[3][r]);
      }
    }
    __syncthreads();

    // ---- cell update + write h(t+1) (agent store), ocat (plain) ----
    const int t_o = d ? (511 - t) : t;
    u16* hnxt = hbd + (size_t)((t+1)&1)*32768;
    for (int p=tid; p<512; p+=256){
      int b = p>>3, c2 = (p&7)*2;
      float i0 = sigm(ldsg[0][b][c2]);
      float i1 = sigm(ldsg[0][b][c2+1]);
      float cn0 = (1.f-i0)*ldsc[b][c2]   + i0*tanh_f(ldsg[1][b][c2]);
      float cn1 = (1.f-i1)*ldsc[b][c2+1] + i1*tanh_f(ldsg[1][b][c2+1]);
      ldsc[b][c2] = cn0; ldsc[b][c2+1] = cn1;
      float hv0 = tanh_f(cn0)*sigm(ldsg[2][b][c2]);
      float hv1 = tanh_f(cn1)*sigm(ldsg[2][b][c2+1]);
      u32 pk = (u32)f2b(hv0) | ((u32)f2b(hv1)<<16);
      __hip_atomic_store((u32*)(hnxt + (size_t)b*512 + n0 + c2), pk,
                         __ATOMIC_RELAXED, __HIP_MEMORY_SCOPE_AGENT);
      *(u32*)(ocat + (((size_t)(b*512 + t_o))<<10) + (d<<9) + n0 + c2) = pk;
    }
    __syncthreads();                     // all waves' stores drained (vmcnt0 + barrier)

    if (tid==0)
      __hip_atomic_fetch_add(ctrd, 1u, __ATOMIC_RELAXED, __HIP_MEMORY_SCOPE_AGENT);

    // prefetch next step's gate-x while the barrier settles
    s16x4 gvn[4];
    if (wave < 3){
      int tn = (t+1 < 512) ? (t+1) : 511;
      const u16* Gtn = G + ((size_t)(d*512 + tn)*96 + ntg)*1024;
      #pragma unroll
      for (int mt=0;mt<4;mt++) gvn[mt] = *(const s16x4*)(Gtn + mt*256 + (lane<<2));
    }
    if (tid==0){
      u32 tg = 32u*(u32)(t+2);
      while (__hip_atomic_load(ctrd, __ATOMIC_RELAXED, __HIP_MEMORY_SCOPE_AGENT) < tg) {}
    }
    asm volatile("" ::: "memory");
    __syncthreads();
    if (wave < 3){
      #pragma unroll
      for (int mt=0;mt<4;mt++) gv[mt] = gvn[mt];
    }
  }
}

extern "C" void kernel_launch(void* const* d_in, const int* in_sizes, int n_in,
                              void* d_out, int out_size, void* d_ws, size_t ws_size,
                              hipStream_t stream)
{
  (void)in_sizes; (void)n_in; (void)out_size;
  if (ws_size < WS_NEED) return;
  const float* x      = (const float*)d_in[0];
  const float* fw_W   = (const float*)d_in[1];
  const float* fw_b   = (const float*)d_in[2];
  const float* bw_W   = (const float*)d_in[3];
  const float* bw_b   = (const float*)d_in[4];
  const float* h0f    = (const float*)d_in[5];
  const float* c0f    = (const float*)d_in[6];
  const float* h0b    = (const float*)d_in[7];
  const float* c0b    = (const float*)d_in[8];
  const float* proj_W = (const float*)d_in[9];
  const float* proj_b = (const float*)d_in[10];
  const float* ipW    = (const float*)d_in[11];
  const float* ipb    = (const float*)d_in[12];
  char* ws = (char*)d_ws;
  u16* WXT  = (u16*)(ws + OFF_WXT);
  u16* WHF  = (u16*)(ws + OFF_WHF);
  u16* PRJT = (u16*)(ws + OFF_PRJT);
  u16* IPJT = (u16*)(ws + OFF_IPJT);
  u16* XB   = (u16*)(ws + OFF_XB);
  u16* GB   = (u16*)(ws + OFF_G);
  u16* OCAT = (u16*)(ws + OFF_OCAT);
  float* INP= (float*)(ws + OFF_INP);
  u16* HB   = (u16*)(ws + OFF_HB);
  u32* CTR  = (u32*)(ws + OFF_CTR);

  hipMemsetAsync(CTR, 0, 768, stream);
  k_convx<<<131072, 256, 0, stream>>>(x, XB);
  k_wxt<<<36864, 256, 0, stream>>>(fw_W, bw_W, WXT);
  k_whf<<<18432, 256, 0, stream>>>(fw_W, bw_W, WHF);
  k_pjt<<<16384, 256, 0, stream>>>(proj_W, ipW, PRJT, IPJT);

  gemm_bt<1><<<2048, 256, 0, stream>>>(XB, IPJT, ipb, 1024, nullptr, 0, INP, nullptr, nullptr, nullptr);

  for (int l=0; l<3; ++l){
    gemm_bt<0><<<3072, 256, 0, stream>>>(XB, WXT + (size_t)l*1572864, fw_b + l*1536, 1024,
                                         GB, 0, nullptr, nullptr, nullptr, nullptr);
    gemm_bt<0><<<3072, 256, 0, stream>>>(XB, WXT + (size_t)(3+l)*1572864, bw_b + l*1536, 1024,
                                         GB + 50331648ull, 1, nullptr, nullptr, nullptr, nullptr);
    {
      const u16* whfl = WHF + (size_t)l*1572864;
      const u16* gbp  = GB;
      u16* hbp = HB;
      const float* p1 = h0f + l*512;
      const float* p2 = c0f + l*512;
      const float* p3 = h0b + l*512;
      const float* p4 = c0b + l*512;
      u16* ocp = OCAT;
      u32* ctp = CTR + l*64;
      void* args[] = { (void*)&whfl, (void*)&gbp, (void*)&hbp,
                       (void*)&p1, (void*)&p2, (void*)&p3, (void*)&p4,
                       (void*)&ocp, (void*)&ctp };
      hipLaunchCooperativeKernel((void*)lstm_rec, dim3(64), dim3(256), args, 0, stream);
    }
    gemm_bt<2><<<2048, 256, 0, stream>>>(OCAT, PRJT + (size_t)l*1048576, proj_b + l*1024, 1024,
                                         nullptr, 0, INP, OCAT, XB,
                                         (l==2) ? (float*)d_out : nullptr);
  }
}

// Round 5
// 16678.239 us; speedup vs baseline: 1.3238x; 1.1068x over previous
//
#include <hip/hip_runtime.h>
#include <stdint.h>

typedef short bf16x8 __attribute__((ext_vector_type(8)));
typedef float f32x4 __attribute__((ext_vector_type(4)));
typedef unsigned int u32;
typedef unsigned short u16;
typedef unsigned long long u64;

// ---------------- workspace layout (bytes) ----------------
#define OFF_WXT  0ull                  // [2][3][1536][1024] bf16  (Wx transposed)
#define OFF_WHF  18874368ull           // [3][2][32][3][16][64][8] bf16 (Wh frags)
#define OFF_PRJT 37748736ull           // [3][1024][1024] bf16 (proj_W^T)
#define OFF_IPJT 44040192ull           // [1024][1024] bf16 (in_proj_W^T)
#define OFF_XB   46137344ull           // [32768][1024] bf16 (activations)
#define OFF_G    113246208ull          // [2][512*96][1024] bf16 (gate-x tiles)
#define OFF_OCAT 314572800ull          // [32768][1024] bf16 (hf|hb)
#define OFF_INP  381681664ull          // [32768][1024] f32 (highway inputs)
#define OFF_HB   515899392ull          // [2][2][64][512] bf16 (h double-buf)
#define OFF_CTR  516161536ull          // [3][2] {arrive,release} lines
#define WS_NEED  516165632ull

__device__ __forceinline__ float b2f(u32 u){ return __uint_as_float(u<<16); }
__device__ __forceinline__ u16 f2b(float f){
  u32 i = __float_as_uint(f);
  return (u16)((i + 0x7FFFu + ((i>>16)&1u))>>16);
}
__device__ __forceinline__ float sigm(float x){ return 1.f/(1.f+__expf(-x)); }
__device__ __forceinline__ float tanh_f(float x){
  x = fminf(fmaxf(x,-15.f),15.f);
  float e = __expf(2.f*x);
  return (e-1.f)/(e+1.f);
}
__device__ __forceinline__ void gl_lds16(const void* g, void* l){
  __builtin_amdgcn_global_load_lds((const __attribute__((address_space(1))) u32*)g,
                                   (__attribute__((address_space(3))) u32*)l, 16, 0, 0);
}

// ---------------- prep kernels ----------------
__global__ void k_convx(const float* __restrict__ x, u16* __restrict__ xb){
  long i = (long)blockIdx.x*blockDim.x + threadIdx.x;   // exactly 33554432 threads
  xb[i] = f2b(x[i]);
}

__global__ void k_wxt(const float* __restrict__ fw, const float* __restrict__ bw, u16* __restrict__ out){
  long o = (long)blockIdx.x*blockDim.x + threadIdx.x;   // 9437184
  int k = (int)(o & 1023);
  long q = o >> 10;
  int nn = (int)(q % 1536); q /= 1536;
  int l = (int)(q % 3); int d = (int)(q / 3);
  const float* W = (d ? bw : fw) + (size_t)l*1536*1536;
  out[o] = f2b(W[(size_t)k*1536 + nn]);
}

__global__ void k_whf(const float* __restrict__ fw, const float* __restrict__ bw, u16* __restrict__ out){
  long o = (long)blockIdx.x*blockDim.x + threadIdx.x;   // exactly 4718592 threads
  int e = (int)(o & 7);
  int lane = (int)((o>>3) & 63);
  int kk = (int)((o>>9) & 15);
  long q = o >> 13;
  int g = (int)(q % 3); q /= 3;
  int wg = (int)(q % 32); q /= 32;
  int d = (int)(q % 2); int l = (int)(q / 2);
  const float* W = (d ? bw : fw) + (size_t)l*1536*1536;
  int row = 1024 + kk*32 + (lane>>4)*8 + e;
  int col = g*512 + wg*16 + (lane&15);
  out[o] = f2b(W[(size_t)row*1536 + col]);
}

__global__ void k_pjt(const float* __restrict__ pw, const float* __restrict__ ipw,
                      u16* __restrict__ pjt, u16* __restrict__ ipjt){
  long o = (long)blockIdx.x*blockDim.x + threadIdx.x;   // 4194304
  if (o < 3145728){
    int k = (int)(o & 1023); int nn = (int)((o>>10) & 1023); int l = (int)(o >> 20);
    pjt[o] = f2b(pw[((size_t)l<<20) + (size_t)k*1024 + nn]);
  } else {
    long o2 = o - 3145728;
    int k = (int)(o2 & 1023); int nn = (int)(o2 >> 10);
    ipjt[o2] = f2b(ipw[(size_t)k*1024 + nn]);
  }
}

// ---------------- tiled bf16 MFMA GEMM (B^T input), fused epilogues ----------------
template<int V>
__global__ __launch_bounds__(256)
void gemm_bt(const u16* __restrict__ A, const u16* __restrict__ Bt,
             const float* __restrict__ bias, int K,
             u16* __restrict__ Gout, int dir,
             float* __restrict__ inputs,
             const u16* __restrict__ ocat, u16* __restrict__ xbout,
             float* __restrict__ dout)
{
  __shared__ u16 As[128*64];
  __shared__ u16 Bs[128*64];
  const int tid = threadIdx.x, wid = tid>>6, lane = tid&63;
  const int wr = wid>>1, wc = wid&1;
  const int mblk = blockIdx.x & 255;
  const int nblk = blockIdx.x >> 8;
  f32x4 acc[4][4];
  #pragma unroll
  for (int i=0;i<4;i++)
    #pragma unroll
    for (int j=0;j<4;j++) acc[i][j] = (f32x4){0.f,0.f,0.f,0.f};
  const size_t Kb = (size_t)K*2;
  const char* Ab = (const char*)A + (size_t)(mblk*128)*Kb;
  const char* Bb = (const char*)Bt + (size_t)(nblk*128)*Kb;
  const int r8 = lane>>3, c8 = lane&7;
  for (int kt=0; kt<K/64; ++kt){
    __syncthreads();
    #pragma unroll
    for (int i=0;i<4;i++){
      const int instr = wid*4 + i;
      const int row = instr*8 + r8;
      const int so = (c8*16) ^ ((row&7)<<4);          // T2 swizzle via pre-swizzled src
      gl_lds16(Ab + (size_t)row*Kb + kt*128 + so, (char*)As + instr*1024);
      gl_lds16(Bb + (size_t)row*Kb + kt*128 + so, (char*)Bs + instr*1024);
    }
    __syncthreads();
    #pragma unroll
    for (int ks=0; ks<2; ++ks){
      bf16x8 af[4], bfv[4];
      #pragma unroll
      for (int mt=0;mt<4;mt++){
        int r = wr*64 + mt*16 + (lane&15);
        int kb = (ks*64 + ((lane>>4)*16)) ^ ((r&7)<<4);
        af[mt] = *(const bf16x8*)((const char*)As + r*128 + kb);
      }
      #pragma unroll
      for (int nt=0;nt<4;nt++){
        int r = wc*64 + nt*16 + (lane&15);
        int kb = (ks*64 + ((lane>>4)*16)) ^ ((r&7)<<4);
        bfv[nt] = *(const bf16x8*)((const char*)Bs + r*128 + kb);
      }
      #pragma unroll
      for (int mt=0;mt<4;mt++)
        #pragma unroll
        for (int nt=0;nt<4;nt++)
          acc[mt][nt] = __builtin_amdgcn_mfma_f32_16x16x32_bf16(af[mt], bfv[nt], acc[mt][nt], 0,0,0);
    }
  }
  const int mb = mblk*128 + wr*64;
  const int nb = nblk*128 + wc*64;
  #pragma unroll
  for (int nt=0;nt<4;nt++){
    const int n = nb + nt*16 + (lane&15);
    const float bv = bias[n];
    #pragma unroll
    for (int mt=0;mt<4;mt++){
      #pragma unroll
      for (int r=0;r<4;r++){
        const int m = mb + mt*16 + (lane>>4)*4 + r;
        float v = acc[mt][nt][r] + bv;
        if (V==0){
          int b = m >> 9, t = m & 511;
          int tp = dir ? (511 - t) : t;
          // tile = (tp, n>>4); per-lane-contiguous frag layout:
          // widx = [lane = ((b>>2)&3)*16 + (n&15)] * 16 + (b>>4)*4 + (b&3)
          size_t tile = (size_t)tp*96 + (n>>4);
          int widx = ((((b>>2)&3)*16 + (n&15))<<4) + (((b>>4)&3)<<2) + (b&3);
          Gout[tile*1024 + widx] = f2b(v);
        } else if (V==1){
          inputs[(size_t)m*1024 + n] = v;
        } else {
          float g = sigm(v);
          size_t a = (size_t)m*1024 + n;
          float o = b2f((u32)ocat[a]);
          float nv = g*o + (1.f-g)*inputs[a];
          if (dout) dout[a] = nv;
          else { inputs[a] = nv; xbout[a] = f2b(nv); }
        }
      }
    }
  }
}

// ---------------- persistent recurrent kernel ----------------
// grid = 16 blocks x 1024 threads. block = (dir d, 64-col slice sub).
// waves 0-11: (gate g = w%3, col-subtile cwg = w/3); W_h [512x16] in 16 B-frags.
// waves 12-15 help stage/cell. Cross-block sync: per-direction arrive counter
// + release flag on separate LLC lines; h exchange via agent (sc0 sc1) ops.
__global__ __launch_bounds__(1024, 1)
void lstm_rec(const u16* __restrict__ Whf, const u16* __restrict__ G,
              u16* __restrict__ hb,
              const float* __restrict__ h0f_, const float* __restrict__ c0f_,
              const float* __restrict__ h0b_, const float* __restrict__ c0b_,
              u16* __restrict__ ocat, u32* __restrict__ ctr)
{
  const int d = blockIdx.x >> 3, sub = blockIdx.x & 7;
  const int tid = threadIdx.x;
  const int wave = tid >> 6, lane = tid & 63;
  const int n0 = sub * 64;
  __shared__ u16 hlds[64*520];          // row stride 1040B (padded)
  __shared__ float ldsg[3][64][67];     // odd stride: conflict-light
  __shared__ float ldsc[64][67];

  const int g = wave % 3;
  const int cwg = wave / 3;
  const bool isgate = (wave < 12);

  bf16x8 w[16];
  if (isgate){
    const int wgg = sub*4 + cwg;
    const u16* wb = Whf + (((size_t)(d*32+wgg)*3 + g)*1024 + (size_t)lane)*8;
    #pragma unroll
    for (int kk=0;kk<16;kk++) w[kk] = *(const bf16x8*)(wb + kk*512);
  }
  const float* h0 = d ? h0b_ : h0f_;
  const float* c0 = d ? c0b_ : c0f_;
  u16* hbd = hb + (size_t)d*65536;      // [2 buf][64][512] bf16
  u32* arr = ctr + d*64;                // arrive counter (own 128B line)
  u32* rel = arr + 32;                  // release flag (next 128B line)

  #pragma unroll
  for (int it=0; it<2; ++it){
    int p = tid + it*1024;              // 2048 col-pairs
    int b = p>>5, c2 = (p&31)*2;
    u32 pk = (u32)f2b(h0[n0+c2]) | ((u32)f2b(h0[n0+c2+1])<<16);
    __hip_atomic_store((u32*)(hbd + (size_t)b*512 + n0 + c2), pk,
                       __ATOMIC_RELAXED, __HIP_MEMORY_SCOPE_AGENT);
    ldsc[b][c2]   = c0[n0+c2];
    ldsc[b][c2+1] = c0[n0+c2+1];
  }
  __syncthreads();
  const int ntg = g*32 + sub*4 + cwg;
  bf16x8 q0{}, q1{};
  if (isgate){
    const u16* Gt = G + ((size_t)(d*512)*96 + ntg)*1024;
    q0 = *(const bf16x8*)(Gt + lane*16);
    q1 = *(const bf16x8*)(Gt + lane*16 + 8);
  }
  if (tid==0){
    u32 old = __hip_atomic_fetch_add(arr, 1u, __ATOMIC_RELAXED, __HIP_MEMORY_SCOPE_AGENT);
    if (old == 7u)
      __hip_atomic_store(rel, 1u, __ATOMIC_RELAXED, __HIP_MEMORY_SCOPE_AGENT);
    while (__hip_atomic_load(rel, __ATOMIC_RELAXED, __HIP_MEMORY_SCOPE_AGENT) < 1u)
      __builtin_amdgcn_s_sleep(1);
  }
  __syncthreads();

  const int c16 = (lane>>4)*16;
  const int colw = cwg*16 + (lane&15);
  for (int t=0; t<512; ++t){
    // ---- stage full h[64][512] into LDS (agent loads: fresh from LLC) ----
    const u64* hsrc = (const u64*)(hbd + (size_t)(t&1)*32768);
    #pragma unroll
    for (int it=0; it<8; ++it){
      int idx = tid + it*1024;          // 8192 u64
      u64 v = __hip_atomic_load(hsrc + idx, __ATOMIC_RELAXED, __HIP_MEMORY_SCOPE_AGENT);
      *(u64*)((char*)hlds + (idx>>7)*1040 + ((idx&127)<<3)) = v;
    }
    __syncthreads();

    if (isgate){
      f32x4 acc0={0.f,0.f,0.f,0.f}, acc1={0.f,0.f,0.f,0.f}, acc2={0.f,0.f,0.f,0.f}, acc3={0.f,0.f,0.f,0.f};
      #pragma unroll
      for (int kk=0;kk<16;kk++){
        const char* base = (const char*)hlds + kk*64 + c16;
        bf16x8 a0 = *(const bf16x8*)(base + ((lane&15)     )*1040);
        bf16x8 a1 = *(const bf16x8*)(base + ((lane&15) + 16)*1040);
        bf16x8 a2 = *(const bf16x8*)(base + ((lane&15) + 32)*1040);
        bf16x8 a3 = *(const bf16x8*)(base + ((lane&15) + 48)*1040);
        acc0 = __builtin_amdgcn_mfma_f32_16x16x32_bf16(a0, w[kk], acc0, 0,0,0);
        acc1 = __builtin_amdgcn_mfma_f32_16x16x32_bf16(a1, w[kk], acc1, 0,0,0);
        acc2 = __builtin_amdgcn_mfma_f32_16x16x32_bf16(a2, w[kk], acc2, 0,0,0);
        acc3 = __builtin_amdgcn_mfma_f32_16x16x32_bf16(a3, w[kk], acc3, 0,0,0);
      }
      const int bb = (lane>>4)*4;
      #pragma unroll
      for (int r=0;r<4;r++){
        ldsg[g][bb+r     ][colw] = acc0[r] + b2f((u32)(u16)q0[r]);
        ldsg[g][bb+r + 16][colw] = acc1[r] + b2f((u32)(u16)q0[4+r]);
        ldsg[g][bb+r + 32][colw] = acc2[r] + b2f((u32)(u16)q1[r]);
        ldsg[g][bb+r + 48][colw] = acc3[r] + b2f((u32)(u16)q1[4+r]);
      }
    }
    __syncthreads();

    // ---- cell update + write h(t+1) (agent), ocat (plain) ----
    const int t_o = d ? (511 - t) : t;
    u16* hnxt = hbd + (size_t)((t+1)&1)*32768;
    #pragma unroll
    for (int it=0; it<2; ++it){
      int p = tid + it*1024;
      int b = p>>5, c2 = (p&31)*2;
      float i0 = sigm(ldsg[0][b][c2]);
      float i1 = sigm(ldsg[0][b][c2+1]);
      float cn0 = (1.f-i0)*ldsc[b][c2]   + i0*tanh_f(ldsg[1][b][c2]);
      float cn1 = (1.f-i1)*ldsc[b][c2+1] + i1*tanh_f(ldsg[1][b][c2+1]);
      ldsc[b][c2] = cn0; ldsc[b][c2+1] = cn1;
      float hv0 = tanh_f(cn0)*sigm(ldsg[2][b][c2]);
      float hv1 = tanh_f(cn1)*sigm(ldsg[2][b][c2+1]);
      u32 pk = (u32)f2b(hv0) | ((u32)f2b(hv1)<<16);
      __hip_atomic_store((u32*)(hnxt + (size_t)b*512 + n0 + c2), pk,
                         __ATOMIC_RELAXED, __HIP_MEMORY_SCOPE_AGENT);
      *(u32*)(ocat + (((size_t)(b*512 + t_o))<<10) + (d<<9) + n0 + c2) = pk;
    }
    __syncthreads();                     // all stores drained before signaling

    u32 myold = 0;
    if (tid==0)
      myold = __hip_atomic_fetch_add(arr, 1u, __ATOMIC_RELAXED, __HIP_MEMORY_SCOPE_AGENT);
    // prefetch next step's gate-x while the barrier settles
    bf16x8 p0{}, p1{};
    if (isgate){
      int tn = (t+1 < 512) ? (t+1) : 511;
      const u16* Gtn = G + ((size_t)(d*512 + tn)*96 + ntg)*1024;
      p0 = *(const bf16x8*)(Gtn + lane*16);
      p1 = *(const bf16x8*)(Gtn + lane*16 + 8);
    }
    if (tid==0){
      u32 tg = 8u*(u32)(t+2);
      if (myold == tg - 1u)
        __hip_atomic_store(rel, (u32)(t+2), __ATOMIC_RELAXED, __HIP_MEMORY_SCOPE_AGENT);
      while (__hip_atomic_load(rel, __ATOMIC_RELAXED, __HIP_MEMORY_SCOPE_AGENT) < (u32)(t+2))
        __builtin_amdgcn_s_sleep(1);
    }
    __syncthreads();
    q0 = p0; q1 = p1;
  }
}

extern "C" void kernel_launch(void* const* d_in, const int* in_sizes, int n_in,
                              void* d_out, int out_size, void* d_ws, size_t ws_size,
                              hipStream_t stream)
{
  (void)in_sizes; (void)n_in; (void)out_size;
  if (ws_size < WS_NEED) return;
  const float* x      = (const float*)d_in[0];
  const float* fw_W   = (const float*)d_in[1];
  const float* fw_b   = (const float*)d_in[2];
  const float* bw_W   = (const float*)d_in[3];
  const float* bw_b   = (const float*)d_in[4];
  const float* h0f    = (const float*)d_in[5];
  const float* c0f    = (const float*)d_in[6];
  const float* h0b    = (const float*)d_in[7];
  const float* c0b    = (const float*)d_in[8];
  const float* proj_W = (const float*)d_in[9];
  const float* proj_b = (const float*)d_in[10];
  const float* ipW    = (const float*)d_in[11];
  const float* ipb    = (const float*)d_in[12];
  char* ws = (char*)d_ws;
  u16* WXT  = (u16*)(ws + OFF_WXT);
  u16* WHF  = (u16*)(ws + OFF_WHF);
  u16* PRJT = (u16*)(ws + OFF_PRJT);
  u16* IPJT = (u16*)(ws + OFF_IPJT);
  u16* XB   = (u16*)(ws + OFF_XB);
  u16* GB   = (u16*)(ws + OFF_G);
  u16* OCAT = (u16*)(ws + OFF_OCAT);
  float* INP= (float*)(ws + OFF_INP);
  u16* HB   = (u16*)(ws + OFF_HB);
  u32* CTR  = (u32*)(ws + OFF_CTR);

  hipMemsetAsync(CTR, 0, 1536, stream);
  k_convx<<<131072, 256, 0, stream>>>(x, XB);
  k_wxt<<<36864, 256, 0, stream>>>(fw_W, bw_W, WXT);
  k_whf<<<18432, 256, 0, stream>>>(fw_W, bw_W, WHF);
  k_pjt<<<16384, 256, 0, stream>>>(proj_W, ipW, PRJT, IPJT);

  gemm_bt<1><<<2048, 256, 0, stream>>>(XB, IPJT, ipb, 1024, nullptr, 0, INP, nullptr, nullptr, nullptr);

  for (int l=0; l<3; ++l){
    gemm_bt<0><<<3072, 256, 0, stream>>>(XB, WXT + (size_t)l*1572864, fw_b + l*1536, 1024,
                                         GB, 0, nullptr, nullptr, nullptr, nullptr);
    gemm_bt<0><<<3072, 256, 0, stream>>>(XB, WXT + (size_t)(3+l)*1572864, bw_b + l*1536, 1024,
                                         GB + 50331648ull, 1, nullptr, nullptr, nullptr, nullptr);
    {
      const u16* whfl = WHF + (size_t)l*1572864;
      const u16* gbp  = GB;
      u16* hbp = HB;
      const float* p1 = h0f + l*512;
      const float* p2 = c0f + l*512;
      const float* p3 = h0b + l*512;
      const float* p4 = c0b + l*512;
      u16* ocp = OCAT;
      u32* ctp = CTR + l*128;
      void* args[] = { (void*)&whfl, (void*)&gbp, (void*)&hbp,
                       (void*)&p1, (void*)&p2, (void*)&p3, (void*)&p4,
                       (void*)&ocp, (void*)&ctp };
      hipLaunchCooperativeKernel((void*)lstm_rec, dim3(16), dim3(1024), args, 0, stream);
    }
    gemm_bt<2><<<2048, 256, 0, stream>>>(OCAT, PRJT + (size_t)l*1048576, proj_b + l*1024, 1024,
                                         nullptr, 0, INP, OCAT, XB,
                                         (l==2) ? (float*)d_out : nullptr);
  }
}

// Round 6
// 7165.006 us; speedup vs baseline: 3.0815x; 2.3277x over previous
//
#include <hip/hip_runtime.h>
#include <stdint.h>

typedef short bf16x8 __attribute__((ext_vector_type(8)));
typedef short s16x4 __attribute__((ext_vector_type(4)));
typedef float f32x4 __attribute__((ext_vector_type(4)));
typedef unsigned int u32;
typedef unsigned short u16;
typedef unsigned long long u64;

// ---------------- workspace layout (bytes) ----------------
#define OFF_WXT  0ull                  // [2][3][1536][1024] bf16  (Wx transposed)
#define OFF_WHF  18874368ull           // [3][2][32][3][16][64][8] bf16 (Wh frags)
#define OFF_PRJT 37748736ull           // [3][1024][1024] bf16 (proj_W^T)
#define OFF_IPJT 44040192ull           // [1024][1024] bf16 (in_proj_W^T)
#define OFF_XB   46137344ull           // [32768][1024] bf16 (activations)
#define OFF_G    113246208ull          // [2][512*96*4][256] bf16 (gate-x frags)
#define OFF_OCAT 314572800ull          // [32768][1024] bf16 (hf|hb)
#define OFF_INP  381681664ull          // [32768][1024] f32 (highway inputs)
#define OFF_HB   515899392ull          // [2][2][64][512] bf16 (h double-buf)
#define OFF_CTR  516161536ull          // [8 groups][{arrive,release} 128B apart]
#define WS_NEED  516165632ull

__device__ __forceinline__ float b2f(u32 u){ return __uint_as_float(u<<16); }
__device__ __forceinline__ u16 f2b(float f){
  u32 i = __float_as_uint(f);
  return (u16)((i + 0x7FFFu + ((i>>16)&1u))>>16);
}
__device__ __forceinline__ float sigm(float x){ return 1.f/(1.f+__expf(-x)); }
__device__ __forceinline__ float tanh_f(float x){
  x = fminf(fmaxf(x,-15.f),15.f);
  float e = __expf(2.f*x);
  return (e-1.f)/(e+1.f);
}
__device__ __forceinline__ void gl_lds16(const void* g, void* l){
  __builtin_amdgcn_global_load_lds((const __attribute__((address_space(1))) u32*)g,
                                   (__attribute__((address_space(3))) u32*)l, 16, 0, 0);
}

// ---------------- prep kernels ----------------
__global__ void k_convx(const float* __restrict__ x, u16* __restrict__ xb){
  long i = (long)blockIdx.x*blockDim.x + threadIdx.x;   // exactly 33554432 threads
  xb[i] = f2b(x[i]);
}

__global__ void k_wxt(const float* __restrict__ fw, const float* __restrict__ bw, u16* __restrict__ out){
  long o = (long)blockIdx.x*blockDim.x + threadIdx.x;   // 9437184
  int k = (int)(o & 1023);
  long q = o >> 10;
  int nn = (int)(q % 1536); q /= 1536;
  int l = (int)(q % 3); int d = (int)(q / 3);
  const float* W = (d ? bw : fw) + (size_t)l*1536*1536;
  out[o] = f2b(W[(size_t)k*1536 + nn]);
}

__global__ void k_whf(const float* __restrict__ fw, const float* __restrict__ bw, u16* __restrict__ out){
  long o = (long)blockIdx.x*blockDim.x + threadIdx.x;   // exactly 4718592 threads
  int e = (int)(o & 7);
  int lane = (int)((o>>3) & 63);
  int kk = (int)((o>>9) & 15);
  long q = o >> 13;
  int g = (int)(q % 3); q /= 3;
  int wg = (int)(q % 32); q /= 32;
  int d = (int)(q % 2); int l = (int)(q / 2);
  const float* W = (d ? bw : fw) + (size_t)l*1536*1536;
  int row = 1024 + kk*32 + (lane>>4)*8 + e;
  int col = g*512 + wg*16 + (lane&15);
  out[o] = f2b(W[(size_t)row*1536 + col]);
}

__global__ void k_pjt(const float* __restrict__ pw, const float* __restrict__ ipw,
                      u16* __restrict__ pjt, u16* __restrict__ ipjt){
  long o = (long)blockIdx.x*blockDim.x + threadIdx.x;   // 4194304
  if (o < 3145728){
    int k = (int)(o & 1023); int nn = (int)((o>>10) & 1023); int l = (int)(o >> 20);
    pjt[o] = f2b(pw[((size_t)l<<20) + (size_t)k*1024 + nn]);
  } else {
    long o2 = o - 3145728;
    int k = (int)(o2 & 1023); int nn = (int)(o2 >> 10);
    ipjt[o2] = f2b(ipw[(size_t)k*1024 + nn]);
  }
}

// ---------------- tiled bf16 MFMA GEMM (B^T input), fused epilogues ----------------
template<int V>
__global__ __launch_bounds__(256)
void gemm_bt(const u16* __restrict__ A, const u16* __restrict__ Bt,
             const float* __restrict__ bias, int K,
             u16* __restrict__ Gout, int dir,
             float* __restrict__ inputs,
             const u16* __restrict__ ocat, u16* __restrict__ xbout,
             float* __restrict__ dout)
{
  __shared__ u16 As[128*64];
  __shared__ u16 Bs[128*64];
  const int tid = threadIdx.x, wid = tid>>6, lane = tid&63;
  const int wr = wid>>1, wc = wid&1;
  const int mblk = blockIdx.x & 255;
  const int nblk = blockIdx.x >> 8;
  f32x4 acc[4][4];
  #pragma unroll
  for (int i=0;i<4;i++)
    #pragma unroll
    for (int j=0;j<4;j++) acc[i][j] = (f32x4){0.f,0.f,0.f,0.f};
  const size_t Kb = (size_t)K*2;
  const char* Ab = (const char*)A + (size_t)(mblk*128)*Kb;
  const char* Bb = (const char*)Bt + (size_t)(nblk*128)*Kb;
  const int r8 = lane>>3, c8 = lane&7;
  for (int kt=0; kt<K/64; ++kt){
    __syncthreads();
    #pragma unroll
    for (int i=0;i<4;i++){
      const int instr = wid*4 + i;
      const int row = instr*8 + r8;
      const int so = (c8*16) ^ ((row&7)<<4);          // T2 swizzle via pre-swizzled src
      gl_lds16(Ab + (size_t)row*Kb + kt*128 + so, (char*)As + instr*1024);
      gl_lds16(Bb + (size_t)row*Kb + kt*128 + so, (char*)Bs + instr*1024);
    }
    __syncthreads();
    #pragma unroll
    for (int ks=0; ks<2; ++ks){
      bf16x8 af[4], bfv[4];
      #pragma unroll
      for (int mt=0;mt<4;mt++){
        int r = wr*64 + mt*16 + (lane&15);
        int kb = (ks*64 + ((lane>>4)*16)) ^ ((r&7)<<4);
        af[mt] = *(const bf16x8*)((const char*)As + r*128 + kb);
      }
      #pragma unroll
      for (int nt=0;nt<4;nt++){
        int r = wc*64 + nt*16 + (lane&15);
        int kb = (ks*64 + ((lane>>4)*16)) ^ ((r&7)<<4);
        bfv[nt] = *(const bf16x8*)((const char*)Bs + r*128 + kb);
      }
      #pragma unroll
      for (int mt=0;mt<4;mt++)
        #pragma unroll
        for (int nt=0;nt<4;nt++)
          acc[mt][nt] = __builtin_amdgcn_mfma_f32_16x16x32_bf16(af[mt], bfv[nt], acc[mt][nt], 0,0,0);
    }
  }
  const int mb = mblk*128 + wr*64;
  const int nb = nblk*128 + wc*64;
  #pragma unroll
  for (int nt=0;nt<4;nt++){
    const int n = nb + nt*16 + (lane&15);
    const float bv = bias[n];
    #pragma unroll
    for (int mt=0;mt<4;mt++){
      #pragma unroll
      for (int r=0;r<4;r++){
        const int m = mb + mt*16 + (lane>>4)*4 + r;
        float v = acc[mt][nt][r] + bv;
        if (V==0){
          int b = m >> 9, t = m & 511;
          int tp = dir ? (511 - t) : t;
          // frag-keyed: [tp][ntile = (n>>9)*32 + ((n&511)>>4)][bi = b>>4][lane'*4 + r']
          // lane' = ((b&15)>>2)*16 + (n&15), r' = b&3
          int brow = b & 15;
          size_t idx = (((size_t)tp*96 + (n>>9)*32 + ((n&511)>>4))*4 + (b>>4))*256
                     + ((brow>>2)<<6) + ((n&15)<<2) + (brow&3);
          Gout[idx] = f2b(v);
        } else if (V==1){
          inputs[(size_t)m*1024 + n] = v;
        } else {
          float g = sigm(v);
          size_t a = (size_t)m*1024 + n;
          float o = b2f((u32)ocat[a]);
          float nv = g*o + (1.f-g)*inputs[a];
          if (dout) dout[a] = nv;
          else { inputs[a] = nv; xbout[a] = f2b(nv); }
        }
      }
    }
  }
}

// ---------------- persistent recurrent kernel ----------------
// grid = 128 blocks x 512 threads: (dir d, batch-slice bi of 16 rows, col-slice
// ci of 32 h-cols). Waves 0-5: (gate g = w>>1, half = w&1) own 16 gate cols;
// W_h [512x16] register-resident. Batch rows are independent -> sync only among
// the 16 col-slice blocks of the same (d,bi) group (8 independent groups).
__global__ __launch_bounds__(512, 1)
void lstm_rec(const u16* __restrict__ Whf, const u16* __restrict__ G,
              u16* __restrict__ hb,
              const float* __restrict__ h0f_, const float* __restrict__ c0f_,
              const float* __restrict__ h0b_, const float* __restrict__ c0b_,
              u16* __restrict__ ocat, u32* __restrict__ ctr, int lay)
{
  const int blk = blockIdx.x;
  const int d  = blk >> 6;
  const int bi = (blk >> 4) & 3;
  const int ci = blk & 15;
  const int tid = threadIdx.x;
  const int wave = tid >> 6, lane = tid & 63;

  __shared__ u16 hlds[16*544];          // row stride 1088B (bank-even for b128)
  __shared__ float ldsg[3][16][36];
  __shared__ float ldsc[16][36];

  const int g = wave >> 1, half = wave & 1;
  const bool isg = (wave < 6);

  bf16x8 w[16];
  if (isg){
    const int wgg = ci*2 + half;
    const u16* wb = Whf + (((size_t)(d*32+wgg)*3 + g)*1024 + (size_t)lane)*8;
    #pragma unroll
    for (int kk=0;kk<16;kk++) w[kk] = *(const bf16x8*)(wb + kk*512);
  }
  const float* h0 = d ? h0b_ : h0f_;
  const float* c0 = d ? c0b_ : c0f_;
  u16* hbd = hb + (size_t)d*65536;                    // [2 parity][64][512] bf16
  const u16* Gd = G + (size_t)d*50331648ull;
  u32* arr = ctr + (size_t)(d*4+bi)*64;               // 256B group stride
  u32* rel = arr + 32;                                // release on its own 128B line
  const u32 abase = (u32)lay * 8208u;                 // 16*(1+512) arrivals/layer
  const u32 rbase = (u32)lay * 513u;

  // init h(0) slice + c0
  if (tid < 256){
    int b = tid >> 4, c2 = (tid & 15)*2;
    int col = ci*32 + c2;
    u32 pk = (u32)f2b(h0[col]) | ((u32)f2b(h0[col+1])<<16);
    __hip_atomic_store((u32*)(hbd + (size_t)(bi*16+b)*512 + col), pk,
                       __ATOMIC_RELAXED, __HIP_MEMORY_SCOPE_AGENT);
    ldsc[b][c2]   = c0[col];
    ldsc[b][c2+1] = c0[col+1];
  }
  __syncthreads();
  const int ntile = g*32 + ci*2 + half;
  s16x4 q{};
  if (isg)
    q = *(const s16x4*)(Gd + (((size_t)0*96 + ntile)*4 + bi)*256 + lane*4);
  if (tid==0){
    u32 old = __hip_atomic_fetch_add(arr, 1u, __ATOMIC_RELAXED, __HIP_MEMORY_SCOPE_AGENT);
    if (old == abase + 15u)
      __hip_atomic_store(rel, rbase + 1u, __ATOMIC_RELAXED, __HIP_MEMORY_SCOPE_AGENT);
    while (__hip_atomic_load(rel, __ATOMIC_RELAXED, __HIP_MEMORY_SCOPE_AGENT) < rbase + 1u)
      __builtin_amdgcn_s_sleep(1);
  }
  __syncthreads();

  const char* abase_lds = (const char*)hlds + (lane&15)*1088 + ((lane>>4)<<4);
  for (int t=0; t<512; ++t){
    // ---- stage h rows [bi*16, +16) (16KB) from LLC ----
    const u64* hsrc = (const u64*)(hbd + (size_t)(t&1)*32768) + (size_t)bi*2048;
    #pragma unroll
    for (int it=0; it<4; ++it){
      int idx = tid + it*512;           // 2048 u64
      u64 v = __hip_atomic_load(hsrc + idx, __ATOMIC_RELAXED, __HIP_MEMORY_SCOPE_AGENT);
      *(u64*)((char*)hlds + (idx>>7)*1088 + ((idx&127)<<3)) = v;
    }
    __syncthreads();

    if (isg){
      f32x4 ea={0.f,0.f,0.f,0.f}, eb={0.f,0.f,0.f,0.f};
      #pragma unroll
      for (int kk=0;kk<16;kk+=2){
        bf16x8 a0 = *(const bf16x8*)(abase_lds + kk*64);
        bf16x8 a1 = *(const bf16x8*)(abase_lds + kk*64 + 64);
        ea = __builtin_amdgcn_mfma_f32_16x16x32_bf16(a0, w[kk],   ea, 0,0,0);
        eb = __builtin_amdgcn_mfma_f32_16x16x32_bf16(a1, w[kk+1], eb, 0,0,0);
      }
      const int bb = (lane>>4)*4;
      const int cc = half*16 + (lane&15);
      #pragma unroll
      for (int r=0;r<4;r++)
        ldsg[g][bb+r][cc] = ea[r] + eb[r] + b2f((u32)(u16)q[r]);
    }
    __syncthreads();

    // ---- cell update + write h(t+1) (agent), ocat (plain) ----
    const int t_o = d ? (511 - t) : t;
    u16* hnxt = hbd + (size_t)((t+1)&1)*32768;
    if (tid < 256){
      int b = tid>>4, c2 = (tid&15)*2;
      float i0 = sigm(ldsg[0][b][c2]);
      float i1 = sigm(ldsg[0][b][c2+1]);
      float cn0 = (1.f-i0)*ldsc[b][c2]   + i0*tanh_f(ldsg[1][b][c2]);
      float cn1 = (1.f-i1)*ldsc[b][c2+1] + i1*tanh_f(ldsg[1][b][c2+1]);
      ldsc[b][c2] = cn0; ldsc[b][c2+1] = cn1;
      float hv0 = tanh_f(cn0)*sigm(ldsg[2][b][c2]);
      float hv1 = tanh_f(cn1)*sigm(ldsg[2][b][c2+1]);
      u32 pk = (u32)f2b(hv0) | ((u32)f2b(hv1)<<16);
      int gb = bi*16 + b, col = ci*32 + c2;
      __hip_atomic_store((u32*)(hnxt + (size_t)gb*512 + col), pk,
                         __ATOMIC_RELAXED, __HIP_MEMORY_SCOPE_AGENT);
      *(u32*)(ocat + (((size_t)(gb*512 + t_o))<<10) + (d<<9) + col) = pk;
    }
    __syncthreads();                     // drain stores before signaling

    u32 myold = 0;
    if (tid==0)
      myold = __hip_atomic_fetch_add(arr, 1u, __ATOMIC_RELAXED, __HIP_MEMORY_SCOPE_AGENT);
    // prefetch next step's gate-x while the barrier settles
    s16x4 qn{};
    if (isg){
      int tn = (t+1 < 512) ? (t+1) : 511;
      qn = *(const s16x4*)(Gd + (((size_t)tn*96 + ntile)*4 + bi)*256 + lane*4);
    }
    if (tid==0){
      u32 tg = abase + 16u*(u32)(t+2);
      if (myold == tg - 1u)
        __hip_atomic_store(rel, rbase + (u32)(t+2), __ATOMIC_RELAXED, __HIP_MEMORY_SCOPE_AGENT);
      while (__hip_atomic_load(rel, __ATOMIC_RELAXED, __HIP_MEMORY_SCOPE_AGENT) < rbase + (u32)(t+2))
        __builtin_amdgcn_s_sleep(1);
    }
    __syncthreads();
    q = qn;
  }
}

extern "C" void kernel_launch(void* const* d_in, const int* in_sizes, int n_in,
                              void* d_out, int out_size, void* d_ws, size_t ws_size,
                              hipStream_t stream)
{
  (void)in_sizes; (void)n_in; (void)out_size;
  if (ws_size < WS_NEED) return;
  const float* x      = (const float*)d_in[0];
  const float* fw_W   = (const float*)d_in[1];
  const float* fw_b   = (const float*)d_in[2];
  const float* bw_W   = (const float*)d_in[3];
  const float* bw_b   = (const float*)d_in[4];
  const float* h0f    = (const float*)d_in[5];
  const float* c0f    = (const float*)d_in[6];
  const float* h0b    = (const float*)d_in[7];
  const float* c0b    = (const float*)d_in[8];
  const float* proj_W = (const float*)d_in[9];
  const float* proj_b = (const float*)d_in[10];
  const float* ipW    = (const float*)d_in[11];
  const float* ipb    = (const float*)d_in[12];
  char* ws = (char*)d_ws;
  u16* WXT  = (u16*)(ws + OFF_WXT);
  u16* WHF  = (u16*)(ws + OFF_WHF);
  u16* PRJT = (u16*)(ws + OFF_PRJT);
  u16* IPJT = (u16*)(ws + OFF_IPJT);
  u16* XB   = (u16*)(ws + OFF_XB);
  u16* GB   = (u16*)(ws + OFF_G);
  u16* OCAT = (u16*)(ws + OFF_OCAT);
  float* INP= (float*)(ws + OFF_INP);
  u16* HB   = (u16*)(ws + OFF_HB);
  u32* CTR  = (u32*)(ws + OFF_CTR);

  hipMemsetAsync(CTR, 0, 2048, stream);
  k_convx<<<131072, 256, 0, stream>>>(x, XB);
  k_wxt<<<36864, 256, 0, stream>>>(fw_W, bw_W, WXT);
  k_whf<<<18432, 256, 0, stream>>>(fw_W, bw_W, WHF);
  k_pjt<<<16384, 256, 0, stream>>>(proj_W, ipW, PRJT, IPJT);

  gemm_bt<1><<<2048, 256, 0, stream>>>(XB, IPJT, ipb, 1024, nullptr, 0, INP, nullptr, nullptr, nullptr);

  for (int l=0; l<3; ++l){
    gemm_bt<0><<<3072, 256, 0, stream>>>(XB, WXT + (size_t)l*1572864, fw_b + l*1536, 1024,
                                         GB, 0, nullptr, nullptr, nullptr, nullptr);
    gemm_bt<0><<<3072, 256, 0, stream>>>(XB, WXT + (size_t)(3+l)*1572864, bw_b + l*1536, 1024,
                                         GB + 50331648ull, 1, nullptr, nullptr, nullptr, nullptr);
    {
      const u16* whfl = WHF + (size_t)l*1572864;
      const u16* gbp  = GB;
      u16* hbp = HB;
      const float* p1 = h0f + l*512;
      const float* p2 = c0f + l*512;
      const float* p3 = h0b + l*512;
      const float* p4 = c0b + l*512;
      u16* ocp = OCAT;
      u32* ctp = CTR;
      int lay = l;
      void* args[] = { (void*)&whfl, (void*)&gbp, (void*)&hbp,
                       (void*)&p1, (void*)&p2, (void*)&p3, (void*)&p4,
                       (void*)&ocp, (void*)&ctp, (void*)&lay };
      hipLaunchCooperativeKernel((void*)lstm_rec, dim3(128), dim3(512), args, 0, stream);
    }
    gemm_bt<2><<<2048, 256, 0, stream>>>(OCAT, PRJT + (size_t)l*1048576, proj_b + l*1024, 1024,
                                         nullptr, 0, INP, OCAT, XB,
                                         (l==2) ? (float*)d_out : nullptr);
  }
}

// Round 8
// 6287.313 us; speedup vs baseline: 3.5116x; 1.1396x over previous
//
#include <hip/hip_runtime.h>
#include <stdint.h>

typedef short bf16x8 __attribute__((ext_vector_type(8)));
typedef short s16x4 __attribute__((ext_vector_type(4)));
typedef float f32x4 __attribute__((ext_vector_type(4)));
typedef unsigned int u32;
typedef unsigned short u16;
typedef unsigned long long u64;

// ---------------- workspace layout (bytes) ----------------
#define OFF_WXT  0ull                  // [2][3][1536][1024] bf16  (Wx transposed)
#define OFF_WHF  18874368ull           // [3][2][32][3][16][64][8] bf16 (Wh frags)
#define OFF_CTR  28311552ull           // [8 groups][16 producers] flag lines (128B)
#define OFF_PRJT 37748736ull           // [3][1024][1024] bf16 (proj_W^T)
#define OFF_IPJT 44040192ull           // [1024][1024] bf16 (in_proj_W^T)
#define OFF_XB   46137344ull           // [32768][1024] bf16 (activations)
#define OFF_G    113246208ull          // [2][512*96*4][256] bf16 (gate-x frags)
#define OFF_OCAT 314572800ull          // [32768][1024] bf16 (hf|hb)
#define OFF_INP  381681664ull          // [32768][1024] f32 (highway inputs)
#define OFF_HB   515899392ull          // [2][2][64][512] bf16 (h double-buf)
#define WS_NEED  516161536ull

__device__ __forceinline__ float b2f(u32 u){ return __uint_as_float(u<<16); }
__device__ __forceinline__ u16 f2b(float f){
  u32 i = __float_as_uint(f);
  return (u16)((i + 0x7FFFu + ((i>>16)&1u))>>16);
}
__device__ __forceinline__ float sigm(float x){ return 1.f/(1.f+__expf(-x)); }
__device__ __forceinline__ float tanh_f(float x){
  x = fminf(fmaxf(x,-15.f),15.f);
  float e = __expf(2.f*x);
  return (e-1.f)/(e+1.f);
}
__device__ __forceinline__ void gl_lds16(const void* g, void* l){
  __builtin_amdgcn_global_load_lds((const __attribute__((address_space(1))) u32*)g,
                                   (__attribute__((address_space(3))) u32*)l, 16, 0, 0);
}

// ---------------- prep kernels (coalesced) ----------------
__global__ void k_convx(const float4* __restrict__ x, u64* __restrict__ xb){
  long i = (long)blockIdx.x*blockDim.x + threadIdx.x;   // 8388608 threads
  float4 v = x[i];
  xb[i] = (u64)f2b(v.x) | ((u64)f2b(v.y)<<16) | ((u64)f2b(v.z)<<32) | ((u64)f2b(v.w)<<48);
}

// generic 64x64 LDS-tiled transpose f32 -> bf16 for WXT / PRJT / IPJT
__global__ __launch_bounds__(256)
void k_tr(const float* __restrict__ fw, const float* __restrict__ bw,
          const float* __restrict__ pw, const float* __restrict__ ipw,
          u16* __restrict__ wxt, u16* __restrict__ pjt, u16* __restrict__ ipjt){
  __shared__ u16 lds[64][66];
  const int b = blockIdx.x;                 // 3328 total
  const float* src; u16* dst; int srcLD, dstLD, r0, c0;
  if (b < 2304){                            // WXT: 6 mats x (16 k-tiles x 24 n-tiles)
    int mat = b / 384, tt = b % 384;
    int kt = tt % 16, nt = tt / 16;
    int d = mat / 3, l = mat % 3;
    src = (d ? bw : fw) + (size_t)l*1536*1536; srcLD = 1536;
    dst = wxt + (size_t)mat*1536*1024;        dstLD = 1024;
    r0 = kt*64; c0 = nt*64;
  } else if (b < 3072){                     // PRJT: 3 x (16x16)
    int bb = b - 2304, mat = bb / 256, tt = bb % 256;
    int kt = tt % 16, nt = tt / 16;
    src = pw + (size_t)mat*1048576; srcLD = 1024;
    dst = pjt + (size_t)mat*1048576; dstLD = 1024;
    r0 = kt*64; c0 = nt*64;
  } else {                                  // IPJT: 16x16
    int tt = b - 3072;
    int kt = tt % 16, nt = tt / 16;
    src = ipw; srcLD = 1024; dst = ipjt; dstLD = 1024;
    r0 = kt*64; c0 = nt*64;
  }
  const int tr = threadIdx.x >> 6, tc = threadIdx.x & 63;
  #pragma unroll
  for (int i=0;i<16;i++){
    int r = i*4 + tr;
    lds[r][tc] = f2b(src[(size_t)(r0+r)*srcLD + c0 + tc]);
  }
  __syncthreads();
  #pragma unroll
  for (int i=0;i<16;i++){
    int nr = i*4 + tr;
    dst[(size_t)(c0+nr)*dstLD + r0 + tc] = lds[tc][nr];
  }
}

// Wh fragment pack, coalesced reads via LDS tile
__global__ __launch_bounds__(256)
void k_whf2(const float* __restrict__ fw, const float* __restrict__ bw, u16* __restrict__ out){
  __shared__ u16 lds[64][66];
  const int b = blockIdx.x;                 // 1152 = 6 mats x (8 r-tiles x 24 c-tiles)
  const int mat = b / 192, tt = b % 192;
  const int rt = tt & 7, ct = tt >> 3;
  const int l = mat >> 1, d = mat & 1;
  const float* W = (d ? bw : fw) + (size_t)l*1536*1536;
  const int tr = threadIdx.x >> 6, tc = threadIdx.x & 63;
  #pragma unroll
  for (int i=0;i<16;i++){
    int r = i*4 + tr;
    lds[r][tc] = f2b(W[(size_t)(1024 + rt*64 + r)*1536 + ct*64 + tc]);
  }
  __syncthreads();
  const int t = threadIdx.x;
  const int lane = t >> 2;
  const int e0 = (t & 3)*2;
  u32* o32 = (u32*)out;
  #pragma unroll
  for (int kkl=0; kkl<2; ++kkl){
    int rl = kkl*32 + (lane>>4)*8 + e0;
    int kk = rt*2 + kkl;
    #pragma unroll
    for (int cg=0; cg<4; ++cg){
      int col = ct*64 + cg*16;
      int g = col >> 9;
      int wg = (col & 511) >> 4;
      size_t base16 = (size_t)l*1572864 + (size_t)((d*32+wg)*3 + g)*8192 + (size_t)kk*512;
      u16 lo = lds[rl    ][cg*16 + (lane&15)];
      u16 hi = lds[rl + 1][cg*16 + (lane&15)];
      o32[base16/2 + t] = (u32)lo | ((u32)hi<<16);
    }
  }
}

// ---------------- tiled bf16 MFMA GEMM (B^T input), fused epilogues ----------------
template<int V>
__global__ __launch_bounds__(256)
void gemm_bt(const u16* __restrict__ A, const u16* __restrict__ Bt,
             const float* __restrict__ bias, int K,
             u16* __restrict__ Gout, int dir,
             float* __restrict__ inputs,
             const u16* __restrict__ ocat, u16* __restrict__ xbout,
             float* __restrict__ dout)
{
  __shared__ u16 As[128*64];
  __shared__ u16 Bs[128*64];
  const int tid = threadIdx.x, wid = tid>>6, lane = tid&63;
  const int wr = wid>>1, wc = wid&1;
  const int mblk = blockIdx.x & 255;
  const int nblk = blockIdx.x >> 8;
  f32x4 acc[4][4];
  #pragma unroll
  for (int i=0;i<4;i++)
    #pragma unroll
    for (int j=0;j<4;j++) acc[i][j] = (f32x4){0.f,0.f,0.f,0.f};
  const size_t Kb = (size_t)K*2;
  const char* Ab = (const char*)A + (size_t)(mblk*128)*Kb;
  const char* Bb = (const char*)Bt + (size_t)(nblk*128)*Kb;
  const int r8 = lane>>3, c8 = lane&7;
  for (int kt=0; kt<K/64; ++kt){
    __syncthreads();
    #pragma unroll
    for (int i=0;i<4;i++){
      const int instr = wid*4 + i;
      const int row = instr*8 + r8;
      const int so = (c8*16) ^ ((row&7)<<4);          // T2 swizzle via pre-swizzled src
      gl_lds16(Ab + (size_t)row*Kb + kt*128 + so, (char*)As + instr*1024);
      gl_lds16(Bb + (size_t)row*Kb + kt*128 + so, (char*)Bs + instr*1024);
    }
    __syncthreads();
    #pragma unroll
    for (int ks=0; ks<2; ++ks){
      bf16x8 af[4], bfv[4];
      #pragma unroll
      for (int mt=0;mt<4;mt++){
        int r = wr*64 + mt*16 + (lane&15);
        int kb = (ks*64 + ((lane>>4)*16)) ^ ((r&7)<<4);
        af[mt] = *(const bf16x8*)((const char*)As + r*128 + kb);
      }
      #pragma unroll
      for (int nt=0;nt<4;nt++){
        int r = wc*64 + nt*16 + (lane&15);
        int kb = (ks*64 + ((lane>>4)*16)) ^ ((r&7)<<4);
        bfv[nt] = *(const bf16x8*)((const char*)Bs + r*128 + kb);
      }
      #pragma unroll
      for (int mt=0;mt<4;mt++)
        #pragma unroll
        for (int nt=0;nt<4;nt++)
          acc[mt][nt] = __builtin_amdgcn_mfma_f32_16x16x32_bf16(af[mt], bfv[nt], acc[mt][nt], 0,0,0);
    }
  }
  const int mb = mblk*128 + wr*64;
  const int nb = nblk*128 + wc*64;
  #pragma unroll
  for (int nt=0;nt<4;nt++){
    const int n = nb + nt*16 + (lane&15);
    const float bv = bias[n];
    #pragma unroll
    for (int mt=0;mt<4;mt++){
      #pragma unroll
      for (int r=0;r<4;r++){
        const int m = mb + mt*16 + (lane>>4)*4 + r;
        float v = acc[mt][nt][r] + bv;
        if (V==0){
          int b = m >> 9, t = m & 511;
          int tp = dir ? (511 - t) : t;
          int brow = b & 15;
          size_t idx = (((size_t)tp*96 + (n>>9)*32 + ((n&511)>>4))*4 + (b>>4))*256
                     + ((brow>>2)<<6) + ((n&15)<<2) + (brow&3);
          Gout[idx] = f2b(v);
        } else if (V==1){
          inputs[(size_t)m*1024 + n] = v;
        } else {
          float g = sigm(v);
          size_t a = (size_t)m*1024 + n;
          float o = b2f((u32)ocat[a]);
          float nv = g*o + (1.f-g)*inputs[a];
          if (dout) dout[a] = nv;
          else { inputs[a] = nv; xbout[a] = f2b(nv); }
        }
      }
    }
  }
}

// ---------------- persistent recurrent kernel ----------------
// grid = 128 blocks x 512 threads: (dir d, batch-slice bi of 16 rows, col-slice
// ci of 32 h-cols). Sync: per-producer monotone step-stamp flags. RACE FIX
// (round 7): poll BOTH producer flags, then a compiler memory barrier, THEN
// issue the slice loads -- relaxed atomics may otherwise be hoisted above the
// spin loop by the compiler (first-call passed, graph replays diverged).
__global__ __launch_bounds__(512, 1)
void lstm_rec(const u16* __restrict__ Whf, const u16* __restrict__ G,
              u16* __restrict__ hb,
              const float* __restrict__ h0f_, const float* __restrict__ c0f_,
              const float* __restrict__ h0b_, const float* __restrict__ c0b_,
              u16* __restrict__ ocat, u32* __restrict__ ctr, int lay)
{
  const int blk = blockIdx.x;
  const int d  = blk >> 6;
  const int bi = (blk >> 4) & 3;
  const int ci = blk & 15;
  const int tid = threadIdx.x;
  const int wave = tid >> 6, lane = tid & 63;

  __shared__ u16 hlds[16*544];          // logical [16][512], row stride 1088B, XOR-swz
  __shared__ float ldsg[3][16][37];
  __shared__ float ldsc[16][37];

  const int g = wave >> 1, half = wave & 1;
  const bool isg = (wave < 6);

  bf16x8 w[16];
  if (isg){
    const int wgg = ci*2 + half;
    const u16* wb = Whf + (((size_t)(d*32+wgg)*3 + g)*1024 + (size_t)lane)*8;
    #pragma unroll
    for (int kk=0;kk<16;kk++) w[kk] = *(const bf16x8*)(wb + kk*512);
  }
  const float* h0 = d ? h0b_ : h0f_;
  const float* c0 = d ? c0b_ : c0f_;
  u16* hbd = hb + (size_t)d*65536;                    // [2 parity][64][512] bf16
  const u16* Gd = G + (size_t)d*50331648ull;
  u32* av = ctr + (size_t)(d*4+bi)*512;               // group: 16 slots x 32 u32
  const u32 labase = (u32)lay * 513u;

  // init h(0) slice + c0
  if (tid < 256){
    int b = tid >> 4, c2 = (tid & 15)*2;
    int col = ci*32 + c2;
    u32 pk = (u32)f2b(h0[col]) | ((u32)f2b(h0[col+1])<<16);
    __hip_atomic_store((u32*)(hbd + (size_t)(bi*16+b)*512 + col), pk,
                       __ATOMIC_RELAXED, __HIP_MEMORY_SCOPE_AGENT);
    ldsc[b][c2]   = c0[col];
    ldsc[b][c2+1] = c0[col+1];
  }
  __syncthreads();                       // drains init stores
  if (tid==0)
    __hip_atomic_store(av + ci*32, labase + 1u, __ATOMIC_RELAXED, __HIP_MEMORY_SCOPE_AGENT);

  const int ntile = g*32 + ci*2 + half;
  s16x4 q{};
  if (isg)
    q = *(const s16x4*)(Gd + (((size_t)0*96 + ntile)*4 + bi)*256 + lane*4);

  const int srow = lane >> 2;            // staging: row 0..15
  const int part = lane & 3;             // 16B chunk within a producer slice
  const int p0 = wave*2, p1 = wave*2 + 1;
  const int swzw = (srow & 7) << 4;
  char* hlrow = (char*)hlds + srow*1088;
  const int mr = lane & 15;              // MFMA A row
  const char* ab = (const char*)hlds + mr*1088;
  const int c16 = (lane>>4)*16;
  const int swzr = (mr & 7) << 4;

  for (int t=0; t<512; ++t){
    // ---- per-producer poll (both), compiler barrier, THEN stage ----
    const u32 tgt = labase + (u32)t + 1u;
    const u64* hsrc = (const u64*)(hbd + (size_t)(t&1)*32768) + (size_t)bi*2048;
    while (__hip_atomic_load(av + p0*32, __ATOMIC_RELAXED, __HIP_MEMORY_SCOPE_AGENT) < tgt) {}
    while (__hip_atomic_load(av + p1*32, __ATOMIC_RELAXED, __HIP_MEMORY_SCOPE_AGENT) < tgt) {}
    asm volatile("" ::: "memory");      // forbid hoisting the slice loads above the polls
    u64 a0 = __hip_atomic_load(hsrc + srow*128 + p0*8 + part*2,     __ATOMIC_RELAXED, __HIP_MEMORY_SCOPE_AGENT);
    u64 a1 = __hip_atomic_load(hsrc + srow*128 + p0*8 + part*2 + 1, __ATOMIC_RELAXED, __HIP_MEMORY_SCOPE_AGENT);
    u64 b0 = __hip_atomic_load(hsrc + srow*128 + p1*8 + part*2,     __ATOMIC_RELAXED, __HIP_MEMORY_SCOPE_AGENT);
    u64 b1 = __hip_atomic_load(hsrc + srow*128 + p1*8 + part*2 + 1, __ATOMIC_RELAXED, __HIP_MEMORY_SCOPE_AGENT);
    *(u64*)(hlrow + ((p0*64 + part*16) ^ swzw))     = a0;
    *(u64*)(hlrow + ((p0*64 + part*16) ^ swzw) + 8) = a1;
    *(u64*)(hlrow + ((p1*64 + part*16) ^ swzw))     = b0;
    *(u64*)(hlrow + ((p1*64 + part*16) ^ swzw) + 8) = b1;
    __syncthreads();

    if (isg){
      f32x4 ea={0.f,0.f,0.f,0.f}, eb={0.f,0.f,0.f,0.f};
      #pragma unroll
      for (int kk=0;kk<16;kk+=2){
        bf16x8 a0v = *(const bf16x8*)(ab + ((kk*64     + c16) ^ swzr));
        bf16x8 a1v = *(const bf16x8*)(ab + ((kk*64+64  + c16) ^ swzr));
        ea = __builtin_amdgcn_mfma_f32_16x16x32_bf16(a0v, w[kk],   ea, 0,0,0);
        eb = __builtin_amdgcn_mfma_f32_16x16x32_bf16(a1v, w[kk+1], eb, 0,0,0);
      }
      const int bb = (lane>>4)*4;
      const int cc = half*16 + (lane&15);
      #pragma unroll
      for (int r=0;r<4;r++)
        ldsg[g][bb+r][cc] = ea[r] + eb[r] + b2f((u32)(u16)q[r]);
    }
    __syncthreads();

    // ---- cell update + write h(t+1) (agent), ocat (plain) ----
    const int t_o = d ? (511 - t) : t;
    u16* hnxt = hbd + (size_t)((t+1)&1)*32768;
    if (tid < 256){
      int b = tid>>4, c2 = (tid&15)*2;
      float i0 = sigm(ldsg[0][b][c2]);
      float i1 = sigm(ldsg[0][b][c2+1]);
      float cn0 = (1.f-i0)*ldsc[b][c2]   + i0*tanh_f(ldsg[1][b][c2]);
      float cn1 = (1.f-i1)*ldsc[b][c2+1] + i1*tanh_f(ldsg[1][b][c2+1]);
      ldsc[b][c2] = cn0; ldsc[b][c2+1] = cn1;
      float hv0 = tanh_f(cn0)*sigm(ldsg[2][b][c2]);
      float hv1 = tanh_f(cn1)*sigm(ldsg[2][b][c2+1]);
      u32 pk = (u32)f2b(hv0) | ((u32)f2b(hv1)<<16);
      int gb = bi*16 + b, col = ci*32 + c2;
      __hip_atomic_store((u32*)(hnxt + (size_t)gb*512 + col), pk,
                         __ATOMIC_RELAXED, __HIP_MEMORY_SCOPE_AGENT);
      *(u32*)(ocat + (((size_t)(gb*512 + t_o))<<10) + (d<<9) + col) = pk;
    }
    __syncthreads();                     // all stores drained (per-wave vmcnt + barrier)

    if (tid==0)
      __hip_atomic_store(av + ci*32, labase + (u32)t + 2u,
                         __ATOMIC_RELAXED, __HIP_MEMORY_SCOPE_AGENT);
    if (isg){
      int tn = (t+1 < 512) ? (t+1) : 511;
      q = *(const s16x4*)(Gd + (((size_t)tn*96 + ntile)*4 + bi)*256 + lane*4);
    }
  }
}

extern "C" void kernel_launch(void* const* d_in, const int* in_sizes, int n_in,
                              void* d_out, int out_size, void* d_ws, size_t ws_size,
                              hipStream_t stream)
{
  (void)in_sizes; (void)n_in; (void)out_size;
  if (ws_size < WS_NEED) return;
  const float* x      = (const float*)d_in[0];
  const float* fw_W   = (const float*)d_in[1];
  const float* fw_b   = (const float*)d_in[2];
  const float* bw_W   = (const float*)d_in[3];
  const float* bw_b   = (const float*)d_in[4];
  const float* h0f    = (const float*)d_in[5];
  const float* c0f    = (const float*)d_in[6];
  const float* h0b    = (const float*)d_in[7];
  const float* c0b    = (const float*)d_in[8];
  const float* proj_W = (const float*)d_in[9];
  const float* proj_b = (const float*)d_in[10];
  const float* ipW    = (const float*)d_in[11];
  const float* ipb    = (const float*)d_in[12];
  char* ws = (char*)d_ws;
  u16* WXT  = (u16*)(ws + OFF_WXT);
  u16* WHF  = (u16*)(ws + OFF_WHF);
  u16* PRJT = (u16*)(ws + OFF_PRJT);
  u16* IPJT = (u16*)(ws + OFF_IPJT);
  u16* XB   = (u16*)(ws + OFF_XB);
  u16* GB   = (u16*)(ws + OFF_G);
  u16* OCAT = (u16*)(ws + OFF_OCAT);
  float* INP= (float*)(ws + OFF_INP);
  u16* HB   = (u16*)(ws + OFF_HB);
  u32* CTR  = (u32*)(ws + OFF_CTR);

  hipMemsetAsync(CTR, 0, 16384, stream);
  k_convx<<<32768, 256, 0, stream>>>((const float4*)x, (u64*)XB);
  k_tr<<<3328, 256, 0, stream>>>(fw_W, bw_W, proj_W, ipW, WXT, PRJT, IPJT);
  k_whf2<<<1152, 256, 0, stream>>>(fw_W, bw_W, WHF);

  gemm_bt<1><<<2048, 256, 0, stream>>>(XB, IPJT, ipb, 1024, nullptr, 0, INP, nullptr, nullptr, nullptr);

  for (int l=0; l<3; ++l){
    gemm_bt<0><<<3072, 256, 0, stream>>>(XB, WXT + (size_t)l*1572864, fw_b + l*1536, 1024,
                                         GB, 0, nullptr, nullptr, nullptr, nullptr);
    gemm_bt<0><<<3072, 256, 0, stream>>>(XB, WXT + (size_t)(3+l)*1572864, bw_b + l*1536, 1024,
                                         GB + 50331648ull, 1, nullptr, nullptr, nullptr, nullptr);
    {
      const u16* whfl = WHF + (size_t)l*1572864;
      const u16* gbp  = GB;
      u16* hbp = HB;
      const float* p1 = h0f + l*512;
      const float* p2 = c0f + l*512;
      const float* p3 = h0b + l*512;
      const float* p4 = c0b + l*512;
      u16* ocp = OCAT;
      u32* ctp = CTR;
      int lay = l;
      void* args[] = { (void*)&whfl, (void*)&gbp, (void*)&hbp,
                       (void*)&p1, (void*)&p2, (void*)&p3, (void*)&p4,
                       (void*)&ocp, (void*)&ctp, (void*)&lay };
      hipLaunchCooperativeKernel((void*)lstm_rec, dim3(128), dim3(512), args, 0, stream);
    }
    gemm_bt<2><<<2048, 256, 0, stream>>>(OCAT, PRJT + (size_t)l*1048576, proj_b + l*1024, 1024,
                                         nullptr, 0, INP, OCAT, XB,
                                         (l==2) ? (float*)d_out : nullptr);
  }
}